// Round 4
// baseline (5242.538 us; speedup 1.0000x reference)
//
#include <hip/hip_runtime.h>
#include <cstdint>
#include <cstddef>

// ---------------- problem constants ----------------
// B=32, ENC=512, P=196 (14x14), ATT=512, EMB=512, DEC=512, VOCAB=10000, T=63
typedef _Float16 f16;
typedef _Float16 h2 __attribute__((ext_vector_type(2)));
typedef _Float16 h8 __attribute__((ext_vector_type(8)));
typedef float f4v __attribute__((ext_vector_type(4)));

// ---------------- helpers ----------------
__device__ __forceinline__ h2 u2h2(unsigned u) { return __builtin_bit_cast(h2, u); }
__device__ __forceinline__ unsigned h22u(h2 v) { return __builtin_bit_cast(unsigned, v); }

__device__ __forceinline__ unsigned agent_ld_u(const unsigned* p) {
    return __hip_atomic_load(p, __ATOMIC_RELAXED, __HIP_MEMORY_SCOPE_AGENT);
}
__device__ __forceinline__ void agent_st_u(unsigned* p, unsigned v) {
    __hip_atomic_store(p, v, __ATOMIC_RELAXED, __HIP_MEMORY_SCOPE_AGENT);
}
__device__ __forceinline__ unsigned long long agent_ld_u64(const unsigned long long* p) {
    return __hip_atomic_load(p, __ATOMIC_RELAXED, __HIP_MEMORY_SCOPE_AGENT);
}

__device__ __forceinline__ float fdot2(h2 a, h2 b, float c) {
#if __has_builtin(__builtin_amdgcn_fdot2)
    return __builtin_amdgcn_fdot2(a, b, c, false);
#else
    return c + (float)a.x * (float)b.x + (float)a.y * (float)b.y;
#endif
}
__device__ __forceinline__ float sigf(float x) { return 1.0f / (1.0f + expf(-x)); }

// grid barrier: ALL-RELAXED atomics + compiler-only ordering (see R3 notes:
// RELEASE/ACQUIRE would emit buffer_wbl2/buffer_inv and wipe L2 weight
// residency). __syncthreads + explicit vmcnt(0) drain orders the agent stores
// before the arrive flag.
__device__ __forceinline__ void gbar(unsigned* arrive, unsigned* release, unsigned epoch) {
    __syncthreads();
    if (blockIdx.x == 0) {
        if (threadIdx.x < 64) {
            int l = threadIdx.x;
            if (l == 0) {
                asm volatile("s_waitcnt vmcnt(0)" ::: "memory");
                __hip_atomic_store(&arrive[0], epoch, __ATOMIC_RELAXED, __HIP_MEMORY_SCOPE_AGENT);
            }
            bool ok;
            do {
                ok = true;
#pragma unroll
                for (int i = 0; i < 4; ++i)
                    ok = ok && (__hip_atomic_load(&arrive[l + i * 64], __ATOMIC_RELAXED,
                                                  __HIP_MEMORY_SCOPE_AGENT) == epoch);
                if (!ok) __builtin_amdgcn_s_sleep(1);
            } while (__ballot(ok) != ~0ull);
            asm volatile("" ::: "memory");
            if (l == 0)
                __hip_atomic_store(release, epoch, __ATOMIC_RELAXED, __HIP_MEMORY_SCOPE_AGENT);
        }
    } else {
        if (threadIdx.x == 0) {
            asm volatile("s_waitcnt vmcnt(0)" ::: "memory");
            __hip_atomic_store(&arrive[blockIdx.x], epoch, __ATOMIC_RELAXED, __HIP_MEMORY_SCOPE_AGENT);
            while (__hip_atomic_load(release, __ATOMIC_RELAXED, __HIP_MEMORY_SCOPE_AGENT) != epoch)
                __builtin_amdgcn_s_sleep(1);
            asm volatile("" ::: "memory");
        }
    }
    __syncthreads();
}

// ---------------- prep: small weights / biases ----------------
// W_encT[n][k] fp16 ; Wdf8 k8-packed cols [dec_att 512 | f_beta 512]
// b_df = [b_dec | b_fb] ; b_cat[n] = b_ih[n] + b_hh[n]
__global__ void k_prep_w(const float* W_enc, const float* W_dec, const float* W_fb,
                         const float* b_dec, const float* b_fb,
                         const float* b_ih, const float* b_hh,
                         f16* W_encT, f16* Wdf8, float* b_df, float* b_cat) {
    const int S0 = 512 * 512;
    const int S2 = 512 * 1024;
    const int total = S0 + S2 + 1024 + 2048;
    for (int idx = blockIdx.x * 256 + threadIdx.x; idx < total; idx += gridDim.x * 256) {
        int i = idx;
        if (i < S0) { int n = i >> 9, k = i & 511; W_encT[i] = (f16)W_enc[k * 512 + n]; continue; }
        i -= S0;
        if (i < S2) {
            int k8 = i / 8192, r = i % 8192, col = r >> 3, kr = r & 7;
            int k = k8 * 8 + kr;
            float v = (col < 512) ? W_dec[k * 512 + col] : W_fb[k * 512 + (col - 512)];
            Wdf8[i] = (f16)v;
            continue;
        }
        i -= S2;
        if (i < 1024) { b_df[i] = (i < 512) ? b_dec[i] : b_fb[i - 512]; continue; }
        i -= 1024;
        b_cat[i] = b_ih[i] + b_hh[i];
    }
}

// ---------------- prep: tiled transpose W_fc -> W_fcT[n][k] fp16 ----------------
__global__ void k_tr_fc(const float* W_fc, f16* W_fcT) {
    __shared__ float tile[64][65];
    int n0 = blockIdx.x * 64;   // 158 tiles -> 10112 (zero-pad past 10000)
    int k0 = blockIdx.y * 64;   // 8 tiles
    int t = threadIdx.x;
#pragma unroll
    for (int i = 0; i < 16; ++i) {
        int lin = t + i * 256;
        int kl = lin >> 6, nl = lin & 63;
        int n = n0 + nl;
        tile[kl][nl] = (n < 10000) ? W_fc[(long)(k0 + kl) * 10000 + n] : 0.0f;
    }
    __syncthreads();
#pragma unroll
    for (int i = 0; i < 2; ++i) {
        int lin = t + i * 256;
        int r = lin >> 3, cv = lin & 7;
        f16 v[8];
#pragma unroll
        for (int kr = 0; kr < 8; ++kr) v[kr] = (f16)tile[cv * 8 + kr][r];
        *(uint4*)&W_fcT[(long)(n0 + r) * 512 + k0 + cv * 8] = *(uint4*)v;
    }
}

// ---------------- prep: tiled k8-repack [W_ih;W_hh] -> Wcat8[k8][n][kr] ----------------
__global__ void k_pack_cat(const float* W_ih, const float* W_hh, f16* Wcat8) {
    __shared__ float tile[64][65];
    int k0 = blockIdx.x * 64;   // 24 tiles (K=1536)
    int n0 = blockIdx.y * 64;   // 32 tiles (N=2048)
    int t = threadIdx.x;
#pragma unroll
    for (int i = 0; i < 16; ++i) {
        int lin = t + i * 256;
        int kl = lin >> 6, nl = lin & 63;
        int k = k0 + kl;
        float v = (k < 1024) ? W_ih[(long)k * 2048 + n0 + nl]
                             : W_hh[(long)(k - 1024) * 2048 + n0 + nl];
        tile[kl][nl] = v;
    }
    __syncthreads();
#pragma unroll
    for (int i = 0; i < 2; ++i) {
        int lin = t + i * 256;
        int nl = lin & 63, k8l = lin >> 6;
        f16 v[8];
#pragma unroll
        for (int kr = 0; kr < 8; ++kr) v[kr] = (f16)tile[k8l * 8 + kr][nl];
        *(uint4*)&Wcat8[(long)(k0 / 8 + k8l) * 16384 + (long)(n0 + nl) * 8] = *(uint4*)v;
    }
}

// ---------------- prep: enc transpose + mean ----------------
__global__ void k_prep_enc(const float* enc_out, f16* enc_t, float* mean_enc) {
    __shared__ float tile[64][197];
    int b = blockIdx.x >> 3, cc = blockIdx.x & 7, c0 = cc * 64;
    int t = threadIdx.x;
    const float* src = enc_out + ((long)b * 512 + c0) * 196;
    for (int i = 0; i < 49; ++i) {
        int lin = t + i * 256;
        int cl = lin / 196, p = lin % 196;
        tile[cl][p] = src[cl * 196 + p];
    }
    __syncthreads();
    if (t < 64) {
        float s = 0.f;
        for (int p = 0; p < 196; ++p) s += tile[t][p];
        mean_enc[b * 512 + c0 + t] = s * (1.0f / 196.0f);
    }
    __syncthreads();
    int cl = t & 63, pg = t >> 6;
    for (int i = 0; i < 49; ++i) {
        int p = pg * 49 + i;
        enc_t[((long)(b * 196 + p)) * 512 + c0 + cl] = (f16)tile[cl][p];
    }
}

// ---------------- h0/c0 + barrier/tail init ----------------
__global__ void k_h0c0(const float* mean_enc, const float* W_init_h, const float* b_init_h,
                       const float* W_init_c, const float* b_init_c,
                       float* c, f16* h_h, f16* h_all, unsigned* bar) {
    if (blockIdx.x == 64) {
        int t = threadIdx.x;
        for (int i = t; i < 512; i += 256) bar[i] = 0u;
        for (int i = t; i < 32 * 512; i += 256) h_all[(long)2016 * 512 + i] = (f16)0.0f;
        return;
    }
    __shared__ float ms[512];
    int b = blockIdx.x >> 1, which = blockIdx.x & 1;
    const float* W = which ? W_init_c : W_init_h;
    const float* bb = which ? b_init_c : b_init_h;
    int t = threadIdx.x;
    ms[t] = mean_enc[b * 512 + t];
    ms[t + 256] = mean_enc[b * 512 + t + 256];
    __syncthreads();
    for (int jj = 0; jj < 2; ++jj) {
        int j = t + jj * 256;
        float acc = bb[j];
        for (int k = 0; k < 512; ++k) acc += ms[k] * W[k * 512 + j];
        if (which) c[b * 512 + j] = acc;
        else h_h[b * 512 + j] = (f16)acc;
    }
}

// ---------------- enc_att = enc @ W_enc_att + b (fp16 MFMA) ----------------
__global__ __launch_bounds__(256, 2) void k_encatt(const f16* A, const f16* Bt,
                                                   const float* bias, f16* Cout) {
    __shared__ __align__(16) f16 As[128 * 32];
    __shared__ __align__(16) f16 Bs[128 * 32];
    int m0 = blockIdx.x * 128, n0 = blockIdx.y * 128;
    int t = threadIdx.x, w = t >> 6, lane = t & 63;
    int wm = (w >> 1) * 64, wn = (w & 1) * 64;
    int lm = lane & 15, lq = lane >> 4;
    f4v acc[4][4];
    for (int mi = 0; mi < 4; ++mi)
        for (int ni = 0; ni < 4; ++ni) acc[mi][ni] = (f4v){0.f, 0.f, 0.f, 0.f};
    for (int kb = 0; kb < 512; kb += 32) {
        for (int i = 0; i < 2; ++i) {
            int li = t + i * 256;
            int row = li >> 2, q = li & 3;
            *(uint4*)&As[row * 32 + q * 8] = *(const uint4*)&A[(long)(m0 + row) * 512 + kb + q * 8];
            *(uint4*)&Bs[row * 32 + q * 8] = *(const uint4*)&Bt[(long)(n0 + row) * 512 + kb + q * 8];
        }
        __syncthreads();
        h8 af[4], bf[4];
        for (int i = 0; i < 4; ++i) {
            af[i] = *(const h8*)&As[(wm + i * 16 + lm) * 32 + lq * 8];
            bf[i] = *(const h8*)&Bs[(wn + i * 16 + lm) * 32 + lq * 8];
        }
        for (int mi = 0; mi < 4; ++mi)
            for (int ni = 0; ni < 4; ++ni)
                acc[mi][ni] = __builtin_amdgcn_mfma_f32_16x16x32_f16(af[mi], bf[ni], acc[mi][ni], 0, 0, 0);
        __syncthreads();
    }
    for (int mi = 0; mi < 4; ++mi)
        for (int ni = 0; ni < 4; ++ni)
            for (int r = 0; r < 4; ++r) {
                int row = m0 + wm + mi * 16 + lq * 4 + r;
                int col = n0 + wn + ni * 16 + lm;
                Cout[(long)row * 512 + col] = (f16)(acc[mi][ni][r] + bias[col]);
            }
}

// ---------------- final FC: preds = h_all @ W_fc + b_fc (fp16 MFMA, masked) ----------------
__global__ __launch_bounds__(256, 2) void k_fc(const f16* A, const f16* Bt, const float* bias,
                                               const int* cl, float* out) {
    __shared__ __align__(16) f16 As[128 * 32];
    __shared__ __align__(16) f16 Bs[128 * 32];
    int m0 = blockIdx.x * 128, n0 = blockIdx.y * 128;
    int t = threadIdx.x, w = t >> 6, lane = t & 63;
    int wm = (w >> 1) * 64, wn = (w & 1) * 64;
    int lm = lane & 15, lq = lane >> 4;

    bool myact = false;
    if (t < 128) {
        int row = m0 + t;
        if (row < 2016) {
            int b = row / 63, tt = row - b * 63;
            myact = tt < (cl[b] - 1);
        }
    }
    int anyact = __syncthreads_or((int)myact);
    if (!anyact) {
        for (int i = 0; i < 64; ++i) {
            int idx = t + i * 256;
            int row = m0 + (idx >> 7), col = n0 + (idx & 127);
            if (row < 2016 && col < 10000) out[(long)row * 10000 + col] = 0.0f;
        }
        return;
    }

    f4v acc[4][4];
    for (int mi = 0; mi < 4; ++mi)
        for (int ni = 0; ni < 4; ++ni) acc[mi][ni] = (f4v){0.f, 0.f, 0.f, 0.f};
    for (int kb = 0; kb < 512; kb += 32) {
        for (int i = 0; i < 2; ++i) {
            int li = t + i * 256;
            int row = li >> 2, q = li & 3;
            *(uint4*)&As[row * 32 + q * 8] = *(const uint4*)&A[(long)(m0 + row) * 512 + kb + q * 8];
            *(uint4*)&Bs[row * 32 + q * 8] = *(const uint4*)&Bt[(long)(n0 + row) * 512 + kb + q * 8];
        }
        __syncthreads();
        h8 af[4], bf[4];
        for (int i = 0; i < 4; ++i) {
            af[i] = *(const h8*)&As[(wm + i * 16 + lm) * 32 + lq * 8];
            bf[i] = *(const h8*)&Bs[(wn + i * 16 + lm) * 32 + lq * 8];
        }
        for (int mi = 0; mi < 4; ++mi)
            for (int ni = 0; ni < 4; ++ni)
                acc[mi][ni] = __builtin_amdgcn_mfma_f32_16x16x32_f16(af[mi], bf[ni], acc[mi][ni], 0, 0, 0);
        __syncthreads();
    }
    for (int mi = 0; mi < 4; ++mi)
        for (int ni = 0; ni < 4; ++ni)
            for (int r = 0; r < 4; ++r) {
                int row = m0 + wm + mi * 16 + lq * 4 + r;
                int col = n0 + wn + ni * 16 + lm;
                if (row < 2016 && col < 10000) {
                    int b = row / 63, tt = row - b * 63;
                    bool act = tt < (cl[b] - 1);
                    out[(long)row * 10000 + col] = act ? (acc[mi][ni][r] + bias[col]) : 0.0f;
                }
            }
}

// ---------------- persistent recurrent loop (2 barriers/step) ----------------
// ATT phase: blocks 0..31, one per batch. Everything (h, dec_a, gate, scores,
// alpha, awe) lives in LDS; only xh exits via agent stores.
// E phase: all 256 blocks = (bg=bid>>5 -> 4 batches, ng=bid&31 -> 16 j-chans).
__global__ __launch_bounds__(256, 2) void k_loop(
    const f16* Wdf8, const float* b_df,
    const f16* Wcat8, const float* b_cat,
    const f16* enc_att_h, const f16* enc_t,
    const float* W_full, const float* emb, const int* caps, const int* cl,
    float* c, f16* h_h, f16* xh, f16* h_all,
    unsigned* bar) {
    __shared__ __align__(16) unsigned hs_u32[256];   // h row, f16x2
    __shared__ __align__(16) float das[512];         // dec_a + bias
    __shared__ __align__(16) float gs[512];          // sigmoid(f_beta gate)
    __shared__ __align__(16) float ss[208];          // scores
    __shared__ __align__(16) float alps[208];        // alpha
    __shared__ __align__(16) unsigned xsm[4 * 768];  // staged xh rows (E)
    __shared__ __align__(16) float gsm[256];         // gate pre-acts (E)

    const int bid = blockIdx.x, t = threadIdx.x;
    const int lane = t & 63, w = t >> 6;
    unsigned* arrive = bar;
    unsigned* release = bar + 384;

    const bool is_att = bid < 32;
    const int batt = bid;               // ATT batch
    // ATT per-thread step-invariant preloads
    float bd0 = 0.f, bd1 = 0.f, bf0 = 0.f, bf1 = 0.f;
    float4 wf_a = {0, 0, 0, 0}, wf_b = {0, 0, 0, 0};
    if (is_att) {
        bd0 = b_df[t]; bd1 = b_df[t + 256];
        bf0 = b_df[512 + t]; bf1 = b_df[768 + t];
        wf_a = *(const float4*)(W_full + lane * 8);
        wf_b = *(const float4*)(W_full + lane * 8 + 4);
    }
    // E per-thread step-invariant preloads
    const int bg = bid >> 5, ng = bid & 31, b0 = bg * 4;
    const int nl = t & 63, bl = t >> 6;
    const int gidx = nl >> 4, jl = nl & 15;
    const int ncol = gidx * 512 + ng * 16 + jl;
    const float bc = b_cat[ncol];
    const int b_e = b0 + ((t & 31) >> 3);
    const int myclE = cl[b_e];

    for (int step = 0; step < 63; ++step) {
        // ================= ATT phase (blocks 0..31) =================
        if (is_att) {
            const int b = batt;
            // 1) stage h[b] -> LDS (lane-strided agent loads, 1 KB total)
            hs_u32[t] = agent_ld_u((const unsigned*)h_h + b * 256 + t);
            __syncthreads();
            // 2) dec_a + gate: thread t computes dec cols {t,t+256}, fb cols {t,t+256}
            {
                float ad0 = 0.f, ad1 = 0.f, af0 = 0.f, af1 = 0.f;
                const f16* wp = Wdf8;
                for (int k8 = 0; k8 < 64; ++k8) {
                    uint4 hv = *(const uint4*)&hs_u32[k8 * 4];
                    h2 h0 = u2h2(hv.x), h1 = u2h2(hv.y), h2v = u2h2(hv.z), h3 = u2h2(hv.w);
                    const f16* base = wp + (long)k8 * 8192;
                    uint4 wd0 = *(const uint4*)(base + (long)t * 8);
                    uint4 wd1 = *(const uint4*)(base + (long)(t + 256) * 8);
                    uint4 wfb0 = *(const uint4*)(base + (long)(t + 512) * 8);
                    uint4 wfb1 = *(const uint4*)(base + (long)(t + 768) * 8);
                    ad0 = fdot2(h0, u2h2(wd0.x), ad0); ad0 = fdot2(h1, u2h2(wd0.y), ad0);
                    ad0 = fdot2(h2v, u2h2(wd0.z), ad0); ad0 = fdot2(h3, u2h2(wd0.w), ad0);
                    ad1 = fdot2(h0, u2h2(wd1.x), ad1); ad1 = fdot2(h1, u2h2(wd1.y), ad1);
                    ad1 = fdot2(h2v, u2h2(wd1.z), ad1); ad1 = fdot2(h3, u2h2(wd1.w), ad1);
                    af0 = fdot2(h0, u2h2(wfb0.x), af0); af0 = fdot2(h1, u2h2(wfb0.y), af0);
                    af0 = fdot2(h2v, u2h2(wfb0.z), af0); af0 = fdot2(h3, u2h2(wfb0.w), af0);
                    af1 = fdot2(h0, u2h2(wfb1.x), af1); af1 = fdot2(h1, u2h2(wfb1.y), af1);
                    af1 = fdot2(h2v, u2h2(wfb1.z), af1); af1 = fdot2(h3, u2h2(wfb1.w), af1);
                }
                das[t] = ad0 + bd0;
                das[t + 256] = ad1 + bd1;
                gs[t] = sigf(af0 + bf0);
                gs[t + 256] = sigf(af1 + bf1);
            }
            __syncthreads();
            // 3) scores: wave w handles rows p = w + 4i
            {
                float2 d01 = *(const float2*)&das[lane * 8];
                float4 dv0 = *(const float4*)&das[lane * 8];
                float4 dv1 = *(const float4*)&das[lane * 8 + 4];
                (void)d01;
                for (int i = 0; i < 49; ++i) {
                    int p = w + i * 4;
                    uint4 ev = *(const uint4*)(enc_att_h + ((long)b * 196 + p) * 512 + lane * 8);
                    h2 e0 = u2h2(ev.x), e1 = u2h2(ev.y), e2 = u2h2(ev.z), e3 = u2h2(ev.w);
                    float a = 0.f;
                    a += fmaxf((float)e0.x + dv0.x, 0.f) * wf_a.x;
                    a += fmaxf((float)e0.y + dv0.y, 0.f) * wf_a.y;
                    a += fmaxf((float)e1.x + dv0.z, 0.f) * wf_a.z;
                    a += fmaxf((float)e1.y + dv0.w, 0.f) * wf_a.w;
                    a += fmaxf((float)e2.x + dv1.x, 0.f) * wf_b.x;
                    a += fmaxf((float)e2.y + dv1.y, 0.f) * wf_b.y;
                    a += fmaxf((float)e3.x + dv1.z, 0.f) * wf_b.z;
                    a += fmaxf((float)e3.y + dv1.w, 0.f) * wf_b.w;
                    for (int m = 32; m; m >>= 1) a += __shfl_xor(a, m);
                    if (lane == 0) ss[p] = a;
                }
            }
            __syncthreads();
            // 4) softmax over 196 (wave 0)
            if (w == 0) {
                float v[4], e[4];
                float m = -1e30f;
                for (int i = 0; i < 4; ++i) {
                    int p = lane + i * 64;
                    v[i] = (p < 196) ? ss[p] : -1e30f;
                    m = fmaxf(m, v[i]);
                }
                for (int mm = 32; mm; mm >>= 1) m = fmaxf(m, __shfl_xor(m, mm));
                float s = 0.f;
                for (int i = 0; i < 4; ++i) {
                    int p = lane + i * 64;
                    e[i] = (p < 196) ? expf(v[i] - m) : 0.f;
                    s += e[i];
                }
                for (int mm = 32; mm; mm >>= 1) s += __shfl_xor(s, mm);
                float inv = 1.0f / s;
                for (int i = 0; i < 4; ++i) {
                    int p = lane + i * 64;
                    if (p < 196) alps[p] = e[i] * inv;
                }
                if (lane < 12) alps[196 + lane] = 0.f;   // pad for b128 reads
            }
            __syncthreads();
            // 5) awe channels {2t, 2t+1} + xh build
            {
                float awe0 = 0.f, awe1 = 0.f;
                const unsigned* ep = (const unsigned*)enc_t + (long)b * 196 * 256 + t;
                for (int i = 0; i < 49; ++i) {
                    float4 al = *(const float4*)&alps[i * 4];
                    h2 x0 = u2h2(ep[(i * 4 + 0) * 256]);
                    h2 x1 = u2h2(ep[(i * 4 + 1) * 256]);
                    h2 x2 = u2h2(ep[(i * 4 + 2) * 256]);
                    h2 x3 = u2h2(ep[(i * 4 + 3) * 256]);
                    awe0 += al.x * (float)x0.x + al.y * (float)x1.x + al.z * (float)x2.x + al.w * (float)x3.x;
                    awe1 += al.x * (float)x0.y + al.y * (float)x1.y + al.z * (float)x2.y + al.w * (float)x3.y;
                }
                int tok = caps[b * 64 + step];
                float2 ev = *(const float2*)(emb + (long)tok * 512 + 2 * t);
                float g0 = gs[2 * t], g1 = gs[2 * t + 1];
                unsigned* xp = (unsigned*)xh + (long)b * 768;
                h2 pe; pe.x = (f16)ev.x; pe.y = (f16)ev.y;
                agent_st_u(xp + t, h22u(pe));
                h2 pa; pa.x = (f16)(g0 * awe0); pa.y = (f16)(g1 * awe1);
                agent_st_u(xp + 256 + t, h22u(pa));
                agent_st_u(xp + 512 + t, hs_u32[t]);
            }
        }
        gbar(arrive, release, (unsigned)step * 2u + 1u);

        // ================= E phase (all 256 blocks) =================
        {
            // stage xh rows b0..b0+3 -> LDS (u64 lane-strided agent loads)
            const unsigned long long* xsrc = (const unsigned long long*)xh;
#pragma unroll
            for (int i = 0; i < 6; ++i) {
                int lin = t + i * 256;            // 0..1535 over 4 rows x 384 u64
                int row = lin / 384, off = lin - row * 384;
                unsigned long long v = agent_ld_u64(xsrc + (long)(b0 + row) * 384 + off);
                *(unsigned long long*)&xsm[row * 768 + off * 2] = v;
            }
            __syncthreads();
            // gates: thread (bl, nl) -> batch b0+bl, col ncol
            {
                const f16* wp = Wcat8 + (long)ncol * 8;
                const unsigned* xb = &xsm[bl * 768];
                float acc0 = 0.f, acc1 = 0.f;
                for (int k8 = 0; k8 < 192; k8 += 2) {
                    uint4 xa = *(const uint4*)&xb[k8 * 4];
                    uint4 xc = *(const uint4*)&xb[k8 * 4 + 4];
                    uint4 wa = *(const uint4*)(wp + (long)k8 * 16384);
                    uint4 wb = *(const uint4*)(wp + ((long)k8 + 1) * 16384);
                    acc0 = fdot2(u2h2(xa.x), u2h2(wa.x), acc0);
                    acc0 = fdot2(u2h2(xa.y), u2h2(wa.y), acc0);
                    acc0 = fdot2(u2h2(xa.z), u2h2(wa.z), acc0);
                    acc0 = fdot2(u2h2(xa.w), u2h2(wa.w), acc0);
                    acc1 = fdot2(u2h2(xc.x), u2h2(wb.x), acc1);
                    acc1 = fdot2(u2h2(xc.y), u2h2(wb.y), acc1);
                    acc1 = fdot2(u2h2(xc.z), u2h2(wb.z), acc1);
                    acc1 = fdot2(u2h2(xc.w), u2h2(wb.w), acc1);
                }
                gsm[bl * 64 + nl] = acc0 + acc1 + bc;
            }
            __syncthreads();
            // pointwise LSTM + h/c update: threads 0..31 -> (bl2, j-pair)
            if (t < 32) {
                int bl2 = t >> 3, jq = t & 7;
                int b = b0 + bl2;
                int j0 = ng * 16 + jq * 2;
                int base = bl2 * 64;
                int l0 = jq * 2, l1 = jq * 2 + 1;
                float gi0 = gsm[base + l0], gf0 = gsm[base + 16 + l0];
                float gg0 = gsm[base + 32 + l0], go0 = gsm[base + 48 + l0];
                float gi1 = gsm[base + l1], gf1 = gsm[base + 16 + l1];
                float gg1 = gsm[base + 32 + l1], go1 = gsm[base + 48 + l1];
                float2 cold = *(float2*)(c + (long)b * 512 + j0);
                float cn0 = sigf(gf0) * cold.x + sigf(gi0) * tanhf(gg0);
                float hn0 = sigf(go0) * tanhf(cn0);
                float cn1 = sigf(gf1) * cold.y + sigf(gi1) * tanhf(gg1);
                float hn1 = sigf(go1) * tanhf(cn1);
                h2 oldh = u2h2(xsm[bl2 * 768 + 512 + (j0 >> 1)]);
                bool act = step < (myclE - 1);
                float hv0, hv1, cv0, cv1;
                if (act) { hv0 = hn0; hv1 = hn1; cv0 = cn0; cv1 = cn1; }
                else { hv0 = (float)oldh.x; hv1 = (float)oldh.y; cv0 = cold.x; cv1 = cold.y; }
                float2 cw; cw.x = cv0; cw.y = cv1;
                *(float2*)(c + (long)b * 512 + j0) = cw;
                h2 hp; hp.x = (f16)hv0; hp.y = (f16)hv1;
                unsigned pv = h22u(hp);
                agent_st_u((unsigned*)h_h + b * 256 + (j0 >> 1), pv);
                *((unsigned*)h_all + ((long)b * 63 + step) * 256 + (j0 >> 1)) = pv;
            }
        }
        gbar(arrive, release, (unsigned)step * 2u + 2u);
    }
}

// ---------------- launcher ----------------
extern "C" void kernel_launch(void* const* d_in, const int* in_sizes, int n_in,
                              void* d_out, int out_size, void* d_ws, size_t ws_size,
                              hipStream_t stream) {
    const float* encoder_out = (const float*)d_in[0];
    const int* caps = (const int*)d_in[1];
    const int* cl = (const int*)d_in[2];
    const float* emb = (const float*)d_in[3];
    const float* W_enc_att = (const float*)d_in[4];
    const float* b_enc_att = (const float*)d_in[5];
    const float* W_dec_att = (const float*)d_in[6];
    const float* b_dec_att = (const float*)d_in[7];
    const float* W_full_att = (const float*)d_in[8];
    const float* W_init_h = (const float*)d_in[10];
    const float* b_init_h = (const float*)d_in[11];
    const float* W_init_c = (const float*)d_in[12];
    const float* b_init_c = (const float*)d_in[13];
    const float* W_f_beta = (const float*)d_in[14];
    const float* b_f_beta = (const float*)d_in[15];
    const float* W_ih = (const float*)d_in[16];
    const float* b_ih = (const float*)d_in[17];
    const float* W_hh = (const float*)d_in[18];
    const float* b_hh = (const float*)d_in[19];
    const float* W_fc = (const float*)d_in[20];
    const float* b_fc = (const float*)d_in[21];

    char* p = (char*)d_ws;
    auto take = [&](size_t bytes) {
        char* r = p;
        p += (bytes + 255) & ~(size_t)255;
        return r;
    };
    f16* enc_t     = (f16*)take((size_t)32 * 196 * 512 * 2);
    f16* enc_att_h = (f16*)take((size_t)32 * 196 * 512 * 2);
    f16* W_encT    = (f16*)take((size_t)512 * 512 * 2);
    f16* W_fcT     = (f16*)take((size_t)10112 * 512 * 2);
    f16* Wdf8      = (f16*)take((size_t)512 * 1024 * 2);
    f16* Wcat8     = (f16*)take((size_t)1536 * 2048 * 2);
    f16* h_all     = (f16*)take((size_t)2048 * 512 * 2);
    f16* h_h       = (f16*)take((size_t)32 * 512 * 2);
    f16* xh        = (f16*)take((size_t)32 * 1536 * 2);
    float* b_df    = (float*)take(1024 * 4);
    float* b_cat   = (float*)take(2048 * 4);
    float* mean_e  = (float*)take((size_t)32 * 512 * 4);
    float* c_st    = (float*)take((size_t)32 * 512 * 4);
    unsigned* bar  = (unsigned*)take(2048);

    k_prep_w<<<1024, 256, 0, stream>>>(W_enc_att, W_dec_att, W_f_beta,
                                       b_dec_att, b_f_beta, b_ih, b_hh,
                                       W_encT, Wdf8, b_df, b_cat);
    k_tr_fc<<<dim3(158, 8), 256, 0, stream>>>(W_fc, W_fcT);
    k_pack_cat<<<dim3(24, 32), 256, 0, stream>>>(W_ih, W_hh, Wcat8);
    k_prep_enc<<<256, 256, 0, stream>>>(encoder_out, enc_t, mean_e);
    k_h0c0<<<65, 256, 0, stream>>>(mean_e, W_init_h, b_init_h, W_init_c, b_init_c,
                                   c_st, h_h, h_all, bar);
    k_encatt<<<dim3(49, 4), 256, 0, stream>>>(enc_t, W_encT, b_enc_att, enc_att_h);
    k_loop<<<256, 256, 0, stream>>>(Wdf8, b_df, Wcat8, b_cat, enc_att_h, enc_t,
                                    W_full_att, emb, caps, cl,
                                    c_st, h_h, xh, h_all, bar);
    k_fc<<<dim3(16, 79), 256, 0, stream>>>(h_all, W_fcT, b_fc, cl, (float*)d_out);
}

// Round 5
// 3544.973 us; speedup vs baseline: 1.4789x; 1.4789x over previous
//
#include <hip/hip_runtime.h>
#include <cstdint>
#include <cstddef>

// ---------------- problem constants ----------------
// B=32, ENC=512, P=196 (14x14), ATT=512, EMB=512, DEC=512, VOCAB=10000, T=63
typedef _Float16 f16;
typedef _Float16 h2 __attribute__((ext_vector_type(2)));
typedef _Float16 h8 __attribute__((ext_vector_type(8)));
typedef float f4v __attribute__((ext_vector_type(4)));

// ---------------- helpers ----------------
__device__ __forceinline__ h2 u2h2(unsigned u) { return __builtin_bit_cast(h2, u); }
__device__ __forceinline__ unsigned h22u(h2 v) { return __builtin_bit_cast(unsigned, v); }

__device__ __forceinline__ float agent_ld_f(const float* p) {
    return __hip_atomic_load(p, __ATOMIC_RELAXED, __HIP_MEMORY_SCOPE_AGENT);
}
__device__ __forceinline__ void agent_st_f(float* p, float v) {
    __hip_atomic_store(p, v, __ATOMIC_RELAXED, __HIP_MEMORY_SCOPE_AGENT);
}
__device__ __forceinline__ unsigned agent_ld_u(const unsigned* p) {
    return __hip_atomic_load(p, __ATOMIC_RELAXED, __HIP_MEMORY_SCOPE_AGENT);
}
__device__ __forceinline__ void agent_st_u(unsigned* p, unsigned v) {
    __hip_atomic_store(p, v, __ATOMIC_RELAXED, __HIP_MEMORY_SCOPE_AGENT);
}

__device__ __forceinline__ float fdot2(h2 a, h2 b, float c) {
#if __has_builtin(__builtin_amdgcn_fdot2)
    return __builtin_amdgcn_fdot2(a, b, c, false);
#else
    return c + (float)a.x * (float)b.x + (float)a.y * (float)b.y;
#endif
}
__device__ __forceinline__ float sigf(float x) { return 1.0f / (1.0f + expf(-x)); }

// grid barrier: ALL-RELAXED atomics + compiler-only ordering. RELEASE/ACQUIRE
// would emit buffer_wbl2/buffer_inv and wipe L2 weight residency (measured R2).
// Explicit vmcnt(0) drain orders this wave's agent stores before arrive.
__device__ __forceinline__ void gbar(unsigned* arrive, unsigned* release, unsigned epoch) {
    __syncthreads();
    if (blockIdx.x == 0) {
        if (threadIdx.x < 64) {
            int l = threadIdx.x;
            if (l == 0) {
                asm volatile("s_waitcnt vmcnt(0)" ::: "memory");
                __hip_atomic_store(&arrive[0], epoch, __ATOMIC_RELAXED, __HIP_MEMORY_SCOPE_AGENT);
            }
            bool ok;
            do {
                ok = true;
#pragma unroll
                for (int i = 0; i < 4; ++i)
                    ok = ok && (__hip_atomic_load(&arrive[l + i * 64], __ATOMIC_RELAXED,
                                                  __HIP_MEMORY_SCOPE_AGENT) == epoch);
                if (!ok) __builtin_amdgcn_s_sleep(1);
            } while (__ballot(ok) != ~0ull);
            asm volatile("" ::: "memory");
            if (l == 0)
                __hip_atomic_store(release, epoch, __ATOMIC_RELAXED, __HIP_MEMORY_SCOPE_AGENT);
        }
    } else {
        if (threadIdx.x == 0) {
            asm volatile("s_waitcnt vmcnt(0)" ::: "memory");
            __hip_atomic_store(&arrive[blockIdx.x], epoch, __ATOMIC_RELAXED, __HIP_MEMORY_SCOPE_AGENT);
            while (__hip_atomic_load(release, __ATOMIC_RELAXED, __HIP_MEMORY_SCOPE_AGENT) != epoch)
                __builtin_amdgcn_s_sleep(1);
            asm volatile("" ::: "memory");
        }
    }
    __syncthreads();
}

// ---------------- prep: small weights / biases ----------------
// W_encT[n][k] fp16 ; Wdf8 k8-packed cols [dec_att 512 | f_beta 512]
// b_df = [b_dec | b_fb] ; b_cat[n] = b_ih[n] + b_hh[n]
__global__ void k_prep_w(const float* W_enc, const float* W_dec, const float* W_fb,
                         const float* b_dec, const float* b_fb,
                         const float* b_ih, const float* b_hh,
                         f16* W_encT, f16* Wdf8, float* b_df, float* b_cat) {
    const int S0 = 512 * 512;
    const int S2 = 512 * 1024;
    const int total = S0 + S2 + 1024 + 2048;
    for (int idx = blockIdx.x * 256 + threadIdx.x; idx < total; idx += gridDim.x * 256) {
        int i = idx;
        if (i < S0) { int n = i >> 9, k = i & 511; W_encT[i] = (f16)W_enc[k * 512 + n]; continue; }
        i -= S0;
        if (i < S2) {
            int k8 = i / 8192, r = i % 8192, col = r >> 3, kr = r & 7;
            int k = k8 * 8 + kr;
            float v = (col < 512) ? W_dec[k * 512 + col] : W_fb[k * 512 + (col - 512)];
            Wdf8[i] = (f16)v;
            continue;
        }
        i -= S2;
        if (i < 1024) { b_df[i] = (i < 512) ? b_dec[i] : b_fb[i - 512]; continue; }
        i -= 1024;
        b_cat[i] = b_ih[i] + b_hh[i];
    }
}

// ---------------- prep: tiled transpose W_fc -> W_fcT[n][k] fp16 ----------------
__global__ void k_tr_fc(const float* W_fc, f16* W_fcT) {
    __shared__ float tile[64][65];
    int n0 = blockIdx.x * 64;   // 158 tiles -> 10112 (zero-pad past 10000)
    int k0 = blockIdx.y * 64;   // 8 tiles
    int t = threadIdx.x;
#pragma unroll
    for (int i = 0; i < 16; ++i) {
        int lin = t + i * 256;
        int kl = lin >> 6, nl = lin & 63;
        int n = n0 + nl;
        tile[kl][nl] = (n < 10000) ? W_fc[(long)(k0 + kl) * 10000 + n] : 0.0f;
    }
    __syncthreads();
#pragma unroll
    for (int i = 0; i < 2; ++i) {
        int lin = t + i * 256;
        int r = lin >> 3, cv = lin & 7;
        f16 v[8];
#pragma unroll
        for (int kr = 0; kr < 8; ++kr) v[kr] = (f16)tile[cv * 8 + kr][r];
        *(uint4*)&W_fcT[(long)(n0 + r) * 512 + k0 + cv * 8] = *(uint4*)v;
    }
}

// ---------------- prep: k8-repack [W_ih(top 512); W_hh] -> Wpart8[k8][n][kr] (K=1024) ----
__global__ void k_pack_part(const float* W_ih, const float* W_hh, f16* Wpart8) {
    __shared__ float tile[64][65];
    int k0 = blockIdx.x * 64;   // 16 tiles (K=1024)
    int n0 = blockIdx.y * 64;   // 32 tiles (N=2048)
    int t = threadIdx.x;
#pragma unroll
    for (int i = 0; i < 16; ++i) {
        int lin = t + i * 256;
        int kl = lin >> 6, nl = lin & 63;
        int k = k0 + kl;
        float v = (k < 512) ? W_ih[(long)k * 2048 + n0 + nl]
                            : W_hh[(long)(k - 512) * 2048 + n0 + nl];
        tile[kl][nl] = v;
    }
    __syncthreads();
#pragma unroll
    for (int i = 0; i < 2; ++i) {
        int lin = t + i * 256;
        int nl = lin & 63, k8l = lin >> 6;
        f16 v[8];
#pragma unroll
        for (int kr = 0; kr < 8; ++kr) v[kr] = (f16)tile[k8l * 8 + kr][nl];
        *(uint4*)&Wpart8[(long)(k0 / 8 + k8l) * 16384 + (long)(n0 + nl) * 8] = *(uint4*)v;
    }
}

// ---------------- prep: k8-repack W_ih(mid rows 512..1023) -> Wmid8 (K=512) ----------
__global__ void k_pack_mid(const float* W_ih, f16* Wmid8) {
    __shared__ float tile[64][65];
    int k0 = blockIdx.x * 64;   // 8 tiles (K=512)
    int n0 = blockIdx.y * 64;   // 32 tiles
    int t = threadIdx.x;
#pragma unroll
    for (int i = 0; i < 16; ++i) {
        int lin = t + i * 256;
        int kl = lin >> 6, nl = lin & 63;
        tile[kl][nl] = W_ih[(long)(512 + k0 + kl) * 2048 + n0 + nl];
    }
    __syncthreads();
#pragma unroll
    for (int i = 0; i < 2; ++i) {
        int lin = t + i * 256;
        int nl = lin & 63, k8l = lin >> 6;
        f16 v[8];
#pragma unroll
        for (int kr = 0; kr < 8; ++kr) v[kr] = (f16)tile[k8l * 8 + kr][nl];
        *(uint4*)&Wmid8[(long)(k0 / 8 + k8l) * 16384 + (long)(n0 + nl) * 8] = *(uint4*)v;
    }
}

// ---------------- prep: enc transpose + mean ----------------
__global__ void k_prep_enc(const float* enc_out, f16* enc_t, float* mean_enc) {
    __shared__ float tile[64][197];
    int b = blockIdx.x >> 3, cc = blockIdx.x & 7, c0 = cc * 64;
    int t = threadIdx.x;
    const float* src = enc_out + ((long)b * 512 + c0) * 196;
    for (int i = 0; i < 49; ++i) {
        int lin = t + i * 256;
        int cl = lin / 196, p = lin % 196;
        tile[cl][p] = src[cl * 196 + p];
    }
    __syncthreads();
    if (t < 64) {
        float s = 0.f;
        for (int p = 0; p < 196; ++p) s += tile[t][p];
        mean_enc[b * 512 + c0 + t] = s * (1.0f / 196.0f);
    }
    __syncthreads();
    int cl = t & 63, pg = t >> 6;
    for (int i = 0; i < 49; ++i) {
        int p = pg * 49 + i;
        enc_t[((long)(b * 196 + p)) * 512 + c0 + cl] = (f16)tile[cl][p];
    }
}

// ---------------- h0/c0 + barrier/tail init ----------------
__global__ void k_h0c0(const float* mean_enc, const float* W_init_h, const float* b_init_h,
                       const float* W_init_c, const float* b_init_c,
                       float* c, f16* h_h, f16* h_all, unsigned* bar) {
    if (blockIdx.x == 64) {
        int t = threadIdx.x;
        for (int i = t; i < 512; i += 256) bar[i] = 0u;
        for (int i = t; i < 32 * 512; i += 256) h_all[(long)2016 * 512 + i] = (f16)0.0f;
        return;
    }
    __shared__ float ms[512];
    int b = blockIdx.x >> 1, which = blockIdx.x & 1;
    const float* W = which ? W_init_c : W_init_h;
    const float* bb = which ? b_init_c : b_init_h;
    int t = threadIdx.x;
    ms[t] = mean_enc[b * 512 + t];
    ms[t + 256] = mean_enc[b * 512 + t + 256];
    __syncthreads();
    for (int jj = 0; jj < 2; ++jj) {
        int j = t + jj * 256;
        float acc = bb[j];
        for (int k = 0; k < 512; ++k) acc += ms[k] * W[k * 512 + j];
        if (which) c[b * 512 + j] = acc;
        else h_h[b * 512 + j] = (f16)acc;
    }
}

// ---------------- enc_att = enc @ W_enc_att + b (fp16 MFMA) ----------------
__global__ __launch_bounds__(256, 2) void k_encatt(const f16* A, const f16* Bt,
                                                   const float* bias, f16* Cout) {
    __shared__ __align__(16) f16 As[128 * 32];
    __shared__ __align__(16) f16 Bs[128 * 32];
    int m0 = blockIdx.x * 128, n0 = blockIdx.y * 128;
    int t = threadIdx.x, w = t >> 6, lane = t & 63;
    int wm = (w >> 1) * 64, wn = (w & 1) * 64;
    int lm = lane & 15, lq = lane >> 4;
    f4v acc[4][4];
    for (int mi = 0; mi < 4; ++mi)
        for (int ni = 0; ni < 4; ++ni) acc[mi][ni] = (f4v){0.f, 0.f, 0.f, 0.f};
    for (int kb = 0; kb < 512; kb += 32) {
        for (int i = 0; i < 2; ++i) {
            int li = t + i * 256;
            int row = li >> 2, q = li & 3;
            *(uint4*)&As[row * 32 + q * 8] = *(const uint4*)&A[(long)(m0 + row) * 512 + kb + q * 8];
            *(uint4*)&Bs[row * 32 + q * 8] = *(const uint4*)&Bt[(long)(n0 + row) * 512 + kb + q * 8];
        }
        __syncthreads();
        h8 af[4], bf[4];
        for (int i = 0; i < 4; ++i) {
            af[i] = *(const h8*)&As[(wm + i * 16 + lm) * 32 + lq * 8];
            bf[i] = *(const h8*)&Bs[(wn + i * 16 + lm) * 32 + lq * 8];
        }
        for (int mi = 0; mi < 4; ++mi)
            for (int ni = 0; ni < 4; ++ni)
                acc[mi][ni] = __builtin_amdgcn_mfma_f32_16x16x32_f16(af[mi], bf[ni], acc[mi][ni], 0, 0, 0);
        __syncthreads();
    }
    for (int mi = 0; mi < 4; ++mi)
        for (int ni = 0; ni < 4; ++ni)
            for (int r = 0; r < 4; ++r) {
                int row = m0 + wm + mi * 16 + lq * 4 + r;
                int col = n0 + wn + ni * 16 + lm;
                Cout[(long)row * 512 + col] = (f16)(acc[mi][ni][r] + bias[col]);
            }
}

// ---------------- final FC: preds = h_all @ W_fc + b_fc (fp16 MFMA, masked) ----------------
__global__ __launch_bounds__(256, 2) void k_fc(const f16* A, const f16* Bt, const float* bias,
                                               const int* cl, float* out) {
    __shared__ __align__(16) f16 As[128 * 32];
    __shared__ __align__(16) f16 Bs[128 * 32];
    int m0 = blockIdx.x * 128, n0 = blockIdx.y * 128;
    int t = threadIdx.x, w = t >> 6, lane = t & 63;
    int wm = (w >> 1) * 64, wn = (w & 1) * 64;
    int lm = lane & 15, lq = lane >> 4;

    bool myact = false;
    if (t < 128) {
        int row = m0 + t;
        if (row < 2016) {
            int b = row / 63, tt = row - b * 63;
            myact = tt < (cl[b] - 1);
        }
    }
    int anyact = __syncthreads_or((int)myact);
    if (!anyact) {
        for (int i = 0; i < 64; ++i) {
            int idx = t + i * 256;
            int row = m0 + (idx >> 7), col = n0 + (idx & 127);
            if (row < 2016 && col < 10000) out[(long)row * 10000 + col] = 0.0f;
        }
        return;
    }

    f4v acc[4][4];
    for (int mi = 0; mi < 4; ++mi)
        for (int ni = 0; ni < 4; ++ni) acc[mi][ni] = (f4v){0.f, 0.f, 0.f, 0.f};
    for (int kb = 0; kb < 512; kb += 32) {
        for (int i = 0; i < 2; ++i) {
            int li = t + i * 256;
            int row = li >> 2, q = li & 3;
            *(uint4*)&As[row * 32 + q * 8] = *(const uint4*)&A[(long)(m0 + row) * 512 + kb + q * 8];
            *(uint4*)&Bs[row * 32 + q * 8] = *(const uint4*)&Bt[(long)(n0 + row) * 512 + kb + q * 8];
        }
        __syncthreads();
        h8 af[4], bf[4];
        for (int i = 0; i < 4; ++i) {
            af[i] = *(const h8*)&As[(wm + i * 16 + lm) * 32 + lq * 8];
            bf[i] = *(const h8*)&Bs[(wn + i * 16 + lm) * 32 + lq * 8];
        }
        for (int mi = 0; mi < 4; ++mi)
            for (int ni = 0; ni < 4; ++ni)
                acc[mi][ni] = __builtin_amdgcn_mfma_f32_16x16x32_f16(af[mi], bf[ni], acc[mi][ni], 0, 0, 0);
        __syncthreads();
    }
    for (int mi = 0; mi < 4; ++mi)
        for (int ni = 0; ni < 4; ++ni)
            for (int r = 0; r < 4; ++r) {
                int row = m0 + wm + mi * 16 + lq * 4 + r;
                int col = n0 + wn + ni * 16 + lm;
                if (row < 2016 && col < 10000) {
                    int b = row / 63, tt = row - b * 63;
                    bool act = tt < (cl[b] - 1);
                    out[(long)row * 10000 + col] = act ? (acc[mi][ni][r] + bias[col]) : 0.0f;
                }
            }
}

// ---------------- persistent recurrent loop (3 barriers/step, 512-thread blocks) ------
// P1 (256 blocks = 8 bgroups x 32 colgroups): dec_a/f_beta (32 cols, K=512) +
//     partial gates [emb|h]@[Wih_top;Whh] (64 cols, K=1024, K-split across waves).
// P2 (32 blocks, 1/batch): scores + softmax + awe fused in LDS -> xmid = g*awe.
// P3 (256 blocks = 8 bg x 32 jgroups): mid gates (g*awe)@Wih_mid (K=512) +
//     partials + LSTM pointwise -> h, c, h_all.
__global__ __launch_bounds__(512, 2) void k_loop(
    const f16* Wdf8, const float* b_df,
    const f16* Wpart8, const f16* Wmid8, const float* b_cat,
    const f16* enc_att_h, const f16* enc_t,
    const float* W_full, const float* emb, const int* caps, const int* cl,
    float* c, f16* h_h, float* da_gp, float* gp_part, f16* xmid, f16* h_all,
    unsigned* bar) {
    __shared__ __align__(16) unsigned xcat[4 * 512];   // P1 [emb|h] f16x2 (8 KB)
    __shared__ float gred[2 * 4 * 64];                 // P1 gate K-half partials
    __shared__ float dfred[4 * 32 * 2];                // P1 df K-half partials
    __shared__ float das[512], fbs[512];               // P2 dec_a / fb pre
    __shared__ float ss[208], alps[200];               // P2 scores / alpha
    __shared__ float awes[512];                        // P2 awe
    __shared__ __align__(16) unsigned xms[4 * 256];    // P3 staged xmid (4 KB)
    __shared__ float g3[2 * 4 * 64];                   // P3 K-half partials
    __shared__ float gsm[4 * 64];                      // P3 gate values

    const int bid = blockIdx.x, t = threadIdx.x;
    const int lane = t & 63, w = t >> 6;
    unsigned* arrive = bar;
    unsigned* release = bar + 384;

    const int bg = bid >> 5, b0 = bg * 4;
    const int cg = bid & 31;            // P1 colgroup
    const int jg = bid & 31;            // P3 jgroup

    // step-invariant preloads
    float4 wfa = {0, 0, 0, 0}, wfb = {0, 0, 0, 0};
    if (bid < 32) {
        wfa = *(const float4*)(W_full + lane * 8);
        wfb = *(const float4*)(W_full + lane * 8 + 4);
    }
    float bc_g = 0.f, bdf = 0.f;
    if (t < 256) bc_g = b_cat[cg * 64 + (t & 63)];
    else if (t < 384) bdf = b_df[cg * 32 + ((t - 256) & 31)];
    const int nc3 = ((t & 63) >> 4) * 512 + jg * 16 + (t & 15);  // P3 combine col (t<256)
    // P3 LSTM thread constants (t<32)
    const int myb = b0 + (t >> 3);
    const int mycl = (t < 32) ? cl[myb] : 0;
    const int jp = t & 7;
    const int j0 = jg * 16 + jp * 2;
    // P1/P3 GEMV wave constants
    const int wb_ = w & 3, wkh = w >> 2;
    const int n1 = cg * 64 + lane;                                   // P1 gate col
    const int n3 = (lane >> 4) * 512 + jg * 16 + (lane & 15);        // P3 gate col

    for (int step = 0; step < 63; ++step) {
        // ================= P1 =================
        {
#pragma unroll
            for (int i = 0; i < 2; ++i) {
                int idx = t + i * 512;
                int b = idx >> 8, off = idx & 255;
                int tok = caps[(b0 + b) * 64 + step];
                float2 ev = *(const float2*)(emb + (long)tok * 512 + off * 2);
                h2 pe; pe.x = (f16)ev.x; pe.y = (f16)ev.y;
                xcat[b * 512 + off] = h22u(pe);
                xcat[b * 512 + 256 + off] = agent_ld_u((const unsigned*)h_h + (b0 + b) * 256 + off);
            }
            __syncthreads();
            // gate partial (K-half per wave)
            {
                const f16* wp = Wpart8 + (long)n1 * 8 + (long)(wkh * 64) * 16384;
                const unsigned* xb = &xcat[wb_ * 512 + wkh * 256];
                float a0 = 0.f, a1 = 0.f;
                for (int k8 = 0; k8 < 64; k8 += 2) {
                    uint4 wa = *(const uint4*)(wp + (long)k8 * 16384);
                    uint4 wbv = *(const uint4*)(wp + ((long)k8 + 1) * 16384);
                    uint4 xa = *(const uint4*)&xb[k8 * 4];
                    uint4 xc = *(const uint4*)&xb[k8 * 4 + 4];
                    a0 = fdot2(u2h2(xa.x), u2h2(wa.x), a0);
                    a0 = fdot2(u2h2(xa.y), u2h2(wa.y), a0);
                    a0 = fdot2(u2h2(xa.z), u2h2(wa.z), a0);
                    a0 = fdot2(u2h2(xa.w), u2h2(wa.w), a0);
                    a1 = fdot2(u2h2(xc.x), u2h2(wbv.x), a1);
                    a1 = fdot2(u2h2(xc.y), u2h2(wbv.y), a1);
                    a1 = fdot2(u2h2(xc.z), u2h2(wbv.z), a1);
                    a1 = fdot2(u2h2(xc.w), u2h2(wbv.w), a1);
                }
                gred[wkh * 256 + wb_ * 64 + lane] = a0 + a1;
            }
            // dec/f_beta (waves 4..7, K-split by lane half)
            if (w >= 4) {
                int b = w - 4;
                int col = lane & 31, kh2 = lane >> 5;
                int dfcol = cg * 32 + col;
                const f16* wp = Wdf8 + (long)dfcol * 8 + (long)(kh2 * 32) * 8192;
                const unsigned* xb = &xcat[b * 512 + 256 + kh2 * 128];
                float a0 = 0.f;
                for (int k8 = 0; k8 < 32; ++k8) {
                    uint4 wa = *(const uint4*)(wp + (long)k8 * 8192);
                    uint4 xa = *(const uint4*)&xb[k8 * 4];
                    a0 = fdot2(u2h2(xa.x), u2h2(wa.x), a0);
                    a0 = fdot2(u2h2(xa.y), u2h2(wa.y), a0);
                    a0 = fdot2(u2h2(xa.z), u2h2(wa.z), a0);
                    a0 = fdot2(u2h2(xa.w), u2h2(wa.w), a0);
                }
                dfred[(b * 32 + col) * 2 + kh2] = a0;
            }
            __syncthreads();
            if (t < 256) {
                int b = t >> 6, col = t & 63;
                float v = gred[b * 64 + col] + gred[256 + b * 64 + col] + bc_g;
                agent_st_f(gp_part + (long)(b0 + b) * 2048 + cg * 64 + col, v);
            } else if (t < 384) {
                int idx = t - 256, b = idx >> 5, col = idx & 31;
                float v = dfred[(b * 32 + col) * 2] + dfred[(b * 32 + col) * 2 + 1] + bdf;
                agent_st_f(da_gp + (long)(b0 + b) * 1024 + cg * 32 + col, v);
            }
        }
        gbar(arrive, release, (unsigned)step * 3u + 1u);

        // ================= P2 (blocks 0..31) =================
        if (bid < 32) {
            const int b = bid;
            das[t] = agent_ld_f(da_gp + (long)b * 1024 + t);
            fbs[t] = agent_ld_f(da_gp + (long)b * 1024 + 512 + t);
            __syncthreads();
            float4 dv0 = *(const float4*)&das[lane * 8];
            float4 dv1 = *(const float4*)&das[lane * 8 + 4];
            for (int i = 0; i < 25; ++i) {
                int p = w * 25 + i;
                if (p < 196) {
                    uint4 ev = *(const uint4*)(enc_att_h + ((long)b * 196 + p) * 512 + lane * 8);
                    h2 e0 = u2h2(ev.x), e1 = u2h2(ev.y), e2 = u2h2(ev.z), e3 = u2h2(ev.w);
                    float a = 0.f;
                    a += fmaxf((float)e0.x + dv0.x, 0.f) * wfa.x;
                    a += fmaxf((float)e0.y + dv0.y, 0.f) * wfa.y;
                    a += fmaxf((float)e1.x + dv0.z, 0.f) * wfa.z;
                    a += fmaxf((float)e1.y + dv0.w, 0.f) * wfa.w;
                    a += fmaxf((float)e2.x + dv1.x, 0.f) * wfb.x;
                    a += fmaxf((float)e2.y + dv1.y, 0.f) * wfb.y;
                    a += fmaxf((float)e3.x + dv1.z, 0.f) * wfb.z;
                    a += fmaxf((float)e3.y + dv1.w, 0.f) * wfb.w;
                    for (int m = 32; m; m >>= 1) a += __shfl_xor(a, m);
                    if (lane == 0) ss[p] = a;
                }
            }
            __syncthreads();
            if (t < 64) {
                float v[4], e[4];
                float m = -1e30f;
                for (int i = 0; i < 4; ++i) {
                    int p = lane + i * 64;
                    v[i] = (p < 196) ? ss[p] : -1e30f;
                    m = fmaxf(m, v[i]);
                }
                for (int mm = 32; mm; mm >>= 1) m = fmaxf(m, __shfl_xor(m, mm));
                float s = 0.f;
                for (int i = 0; i < 4; ++i) {
                    int p = lane + i * 64;
                    e[i] = (p < 196) ? expf(v[i] - m) : 0.f;
                    s += e[i];
                }
                for (int mm = 32; mm; mm >>= 1) s += __shfl_xor(s, mm);
                float inv = 1.0f / s;
                for (int i = 0; i < 4; ++i) {
                    int p = lane + i * 64;
                    if (p < 196) alps[p] = e[i] * inv;
                }
            }
            __syncthreads();
            {
                float acc = 0.f;
                const f16* ep = enc_t + (long)b * 196 * 512 + t;
#pragma unroll 4
                for (int p = 0; p < 196; ++p) acc += alps[p] * (float)ep[(long)p * 512];
                awes[t] = acc;
            }
            __syncthreads();
            if (t < 256) {
                float a0 = sigf(fbs[2 * t]) * awes[2 * t];
                float a1 = sigf(fbs[2 * t + 1]) * awes[2 * t + 1];
                h2 pa; pa.x = (f16)a0; pa.y = (f16)a1;
                agent_st_u((unsigned*)xmid + b * 256 + t, h22u(pa));
            }
        }
        gbar(arrive, release, (unsigned)step * 3u + 2u);

        // ================= P3 =================
        {
#pragma unroll
            for (int i = 0; i < 2; ++i) {
                int idx = t + i * 512;
                int b = idx >> 8, off = idx & 255;
                xms[b * 256 + off] = agent_ld_u((const unsigned*)xmid + (b0 + b) * 256 + off);
            }
            __syncthreads();
            {
                const f16* wp = Wmid8 + (long)n3 * 8 + (long)(wkh * 32) * 16384;
                const unsigned* xb = &xms[wb_ * 256 + wkh * 128];
                float a0 = 0.f, a1 = 0.f;
                for (int k8 = 0; k8 < 32; k8 += 2) {
                    uint4 wa = *(const uint4*)(wp + (long)k8 * 16384);
                    uint4 wbv = *(const uint4*)(wp + ((long)k8 + 1) * 16384);
                    uint4 xa = *(const uint4*)&xb[k8 * 4];
                    uint4 xc = *(const uint4*)&xb[k8 * 4 + 4];
                    a0 = fdot2(u2h2(xa.x), u2h2(wa.x), a0);
                    a0 = fdot2(u2h2(xa.y), u2h2(wa.y), a0);
                    a0 = fdot2(u2h2(xa.z), u2h2(wa.z), a0);
                    a0 = fdot2(u2h2(xa.w), u2h2(wa.w), a0);
                    a1 = fdot2(u2h2(xc.x), u2h2(wbv.x), a1);
                    a1 = fdot2(u2h2(xc.y), u2h2(wbv.y), a1);
                    a1 = fdot2(u2h2(xc.z), u2h2(wbv.z), a1);
                    a1 = fdot2(u2h2(xc.w), u2h2(wbv.w), a1);
                }
                g3[wkh * 256 + wb_ * 64 + lane] = a0 + a1;
            }
            __syncthreads();
            if (t < 256) {
                int b = t >> 6, l2 = t & 63;
                float v = g3[b * 64 + l2] + g3[256 + b * 64 + l2] +
                          agent_ld_f(gp_part + (long)(b0 + b) * 2048 + nc3);
                gsm[b * 64 + l2] = v;
            }
            __syncthreads();
            if (t < 32) {
                int bl = t >> 3;
                int l0 = jp * 2, l1 = jp * 2 + 1;
                float gi0 = gsm[bl * 64 + l0],      gi1 = gsm[bl * 64 + l1];
                float gf0 = gsm[bl * 64 + 16 + l0], gf1 = gsm[bl * 64 + 16 + l1];
                float gg0 = gsm[bl * 64 + 32 + l0], gg1 = gsm[bl * 64 + 32 + l1];
                float go0 = gsm[bl * 64 + 48 + l0], go1 = gsm[bl * 64 + 48 + l1];
                float2 cold = *(float2*)(c + (long)myb * 512 + j0);
                float cn0 = sigf(gf0) * cold.x + sigf(gi0) * tanhf(gg0);
                float hn0 = sigf(go0) * tanhf(cn0);
                float cn1 = sigf(gf1) * cold.y + sigf(gi1) * tanhf(gg1);
                float hn1 = sigf(go1) * tanhf(cn1);
                h2 oldh = u2h2(agent_ld_u((const unsigned*)h_h + myb * 256 + (j0 >> 1)));
                bool act = step < (mycl - 1);
                float hv0, hv1, cv0, cv1;
                if (act) { hv0 = hn0; hv1 = hn1; cv0 = cn0; cv1 = cn1; }
                else { hv0 = (float)oldh.x; hv1 = (float)oldh.y; cv0 = cold.x; cv1 = cold.y; }
                float2 cw; cw.x = cv0; cw.y = cv1;
                *(float2*)(c + (long)myb * 512 + j0) = cw;
                h2 hp; hp.x = (f16)hv0; hp.y = (f16)hv1;
                unsigned pv = h22u(hp);
                agent_st_u((unsigned*)h_h + myb * 256 + (j0 >> 1), pv);
                *((unsigned*)h_all + ((long)myb * 63 + step) * 256 + (j0 >> 1)) = pv;
            }
        }
        gbar(arrive, release, (unsigned)step * 3u + 3u);
    }
}

// ---------------- launcher ----------------
extern "C" void kernel_launch(void* const* d_in, const int* in_sizes, int n_in,
                              void* d_out, int out_size, void* d_ws, size_t ws_size,
                              hipStream_t stream) {
    const float* encoder_out = (const float*)d_in[0];
    const int* caps = (const int*)d_in[1];
    const int* cl = (const int*)d_in[2];
    const float* emb = (const float*)d_in[3];
    const float* W_enc_att = (const float*)d_in[4];
    const float* b_enc_att = (const float*)d_in[5];
    const float* W_dec_att = (const float*)d_in[6];
    const float* b_dec_att = (const float*)d_in[7];
    const float* W_full_att = (const float*)d_in[8];
    const float* W_init_h = (const float*)d_in[10];
    const float* b_init_h = (const float*)d_in[11];
    const float* W_init_c = (const float*)d_in[12];
    const float* b_init_c = (const float*)d_in[13];
    const float* W_f_beta = (const float*)d_in[14];
    const float* b_f_beta = (const float*)d_in[15];
    const float* W_ih = (const float*)d_in[16];
    const float* b_ih = (const float*)d_in[17];
    const float* W_hh = (const float*)d_in[18];
    const float* b_hh = (const float*)d_in[19];
    const float* W_fc = (const float*)d_in[20];
    const float* b_fc = (const float*)d_in[21];

    char* p = (char*)d_ws;
    auto take = [&](size_t bytes) {
        char* r = p;
        p += (bytes + 255) & ~(size_t)255;
        return r;
    };
    f16* enc_t     = (f16*)take((size_t)32 * 196 * 512 * 2);
    f16* enc_att_h = (f16*)take((size_t)32 * 196 * 512 * 2);
    f16* W_encT    = (f16*)take((size_t)512 * 512 * 2);
    f16* W_fcT     = (f16*)take((size_t)10112 * 512 * 2);
    f16* Wdf8      = (f16*)take((size_t)512 * 1024 * 2);
    f16* Wpart8    = (f16*)take((size_t)1024 * 2048 * 2);
    f16* Wmid8     = (f16*)take((size_t)512 * 2048 * 2);
    f16* h_all     = (f16*)take((size_t)2048 * 512 * 2);
    f16* h_h       = (f16*)take((size_t)32 * 512 * 2);
    f16* xmid      = (f16*)take((size_t)32 * 512 * 2);
    float* b_df    = (float*)take(1024 * 4);
    float* b_cat   = (float*)take(2048 * 4);
    float* mean_e  = (float*)take((size_t)32 * 512 * 4);
    float* c_st    = (float*)take((size_t)32 * 512 * 4);
    float* da_gp   = (float*)take((size_t)32 * 1024 * 4);
    float* gp_part = (float*)take((size_t)32 * 2048 * 4);
    unsigned* bar  = (unsigned*)take(2048);

    k_prep_w<<<1024, 256, 0, stream>>>(W_enc_att, W_dec_att, W_f_beta,
                                       b_dec_att, b_f_beta, b_ih, b_hh,
                                       W_encT, Wdf8, b_df, b_cat);
    k_tr_fc<<<dim3(158, 8), 256, 0, stream>>>(W_fc, W_fcT);
    k_pack_part<<<dim3(16, 32), 256, 0, stream>>>(W_ih, W_hh, Wpart8);
    k_pack_mid<<<dim3(8, 32), 256, 0, stream>>>(W_ih, Wmid8);
    k_prep_enc<<<256, 256, 0, stream>>>(encoder_out, enc_t, mean_e);
    k_h0c0<<<65, 256, 0, stream>>>(mean_e, W_init_h, b_init_h, W_init_c, b_init_c,
                                   c_st, h_h, h_all, bar);
    k_encatt<<<dim3(49, 4), 256, 0, stream>>>(enc_t, W_encT, b_enc_att, enc_att_h);
    k_loop<<<256, 512, 0, stream>>>(Wdf8, b_df, Wpart8, Wmid8, b_cat,
                                    enc_att_h, enc_t, W_full_att, emb, caps, cl,
                                    c_st, h_h, da_gp, gp_part, xmid, h_all, bar);
    k_fc<<<dim3(16, 79), 256, 0, stream>>>(h_all, W_fcT, b_fc, cl, (float*)d_out);
}

// Round 6
// 2173.552 us; speedup vs baseline: 2.4120x; 1.6310x over previous
//
#include <hip/hip_runtime.h>
#include <cstdint>
#include <cstddef>

// ---------------- problem constants ----------------
// B=32, ENC=512, P=196 (14x14), ATT=512, EMB=512, DEC=512, VOCAB=10000, T=63
typedef _Float16 f16;
typedef _Float16 h2 __attribute__((ext_vector_type(2)));
typedef _Float16 h8 __attribute__((ext_vector_type(8)));
typedef float f4v __attribute__((ext_vector_type(4)));

// ---------------- helpers ----------------
__device__ __forceinline__ h2 u2h2(unsigned u) { return __builtin_bit_cast(h2, u); }
__device__ __forceinline__ unsigned h22u(h2 v) { return __builtin_bit_cast(unsigned, v); }
__device__ __forceinline__ float2 u2f2(unsigned long long u) { return __builtin_bit_cast(float2, u); }

__device__ __forceinline__ float agent_ld_f(const float* p) {
    return __hip_atomic_load(p, __ATOMIC_RELAXED, __HIP_MEMORY_SCOPE_AGENT);
}
__device__ __forceinline__ void agent_st_f(float* p, float v) {
    __hip_atomic_store(p, v, __ATOMIC_RELAXED, __HIP_MEMORY_SCOPE_AGENT);
}
__device__ __forceinline__ unsigned agent_ld_u(const unsigned* p) {
    return __hip_atomic_load(p, __ATOMIC_RELAXED, __HIP_MEMORY_SCOPE_AGENT);
}
__device__ __forceinline__ void agent_st_u(unsigned* p, unsigned v) {
    __hip_atomic_store(p, v, __ATOMIC_RELAXED, __HIP_MEMORY_SCOPE_AGENT);
}
__device__ __forceinline__ unsigned long long agent_ld_u64(const unsigned long long* p) {
    return __hip_atomic_load(p, __ATOMIC_RELAXED, __HIP_MEMORY_SCOPE_AGENT);
}

__device__ __forceinline__ float fdot2(h2 a, h2 b, float c) {
#if __has_builtin(__builtin_amdgcn_fdot2)
    return __builtin_amdgcn_fdot2(a, b, c, false);
#else
    return c + (float)a.x * (float)b.x + (float)a.y * (float)b.y;
#endif
}
__device__ __forceinline__ float sigf(float x) { return 1.0f / (1.0f + expf(-x)); }

// grid barrier: ALL-RELAXED atomics + compiler-only ordering. RELEASE/ACQUIRE
// would emit buffer_wbl2/buffer_inv and wipe L2 weight residency (measured R2).
// Explicit vmcnt(0) drain orders this wave's agent stores before arrive.
__device__ __forceinline__ void gbar(unsigned* arrive, unsigned* release, unsigned epoch) {
    __syncthreads();
    if (blockIdx.x == 0) {
        if (threadIdx.x < 64) {
            int l = threadIdx.x;
            if (l == 0) {
                asm volatile("s_waitcnt vmcnt(0)" ::: "memory");
                __hip_atomic_store(&arrive[0], epoch, __ATOMIC_RELAXED, __HIP_MEMORY_SCOPE_AGENT);
            }
            bool ok;
            do {
                ok = true;
#pragma unroll
                for (int i = 0; i < 4; ++i)
                    ok = ok && (__hip_atomic_load(&arrive[l + i * 64], __ATOMIC_RELAXED,
                                                  __HIP_MEMORY_SCOPE_AGENT) == epoch);
                if (!ok) __builtin_amdgcn_s_sleep(1);
            } while (__ballot(ok) != ~0ull);
            asm volatile("" ::: "memory");
            if (l == 0)
                __hip_atomic_store(release, epoch, __ATOMIC_RELAXED, __HIP_MEMORY_SCOPE_AGENT);
        }
    } else {
        if (threadIdx.x == 0) {
            asm volatile("s_waitcnt vmcnt(0)" ::: "memory");
            __hip_atomic_store(&arrive[blockIdx.x], epoch, __ATOMIC_RELAXED, __HIP_MEMORY_SCOPE_AGENT);
            while (__hip_atomic_load(release, __ATOMIC_RELAXED, __HIP_MEMORY_SCOPE_AGENT) != epoch)
                __builtin_amdgcn_s_sleep(1);
            asm volatile("" ::: "memory");
        }
    }
    __syncthreads();
}

// ---------------- prep: small weights / biases ----------------
__global__ void k_prep_w(const float* W_enc, const float* W_dec, const float* W_fb,
                         const float* b_dec, const float* b_fb,
                         const float* b_ih, const float* b_hh,
                         f16* W_encT, f16* Wdf8, float* b_df, float* b_cat) {
    const int S0 = 512 * 512;
    const int S2 = 512 * 1024;
    const int total = S0 + S2 + 1024 + 2048;
    for (int idx = blockIdx.x * 256 + threadIdx.x; idx < total; idx += gridDim.x * 256) {
        int i = idx;
        if (i < S0) { int n = i >> 9, k = i & 511; W_encT[i] = (f16)W_enc[k * 512 + n]; continue; }
        i -= S0;
        if (i < S2) {
            int k8 = i / 8192, r = i % 8192, col = r >> 3, kr = r & 7;
            int k = k8 * 8 + kr;
            float v = (col < 512) ? W_dec[k * 512 + col] : W_fb[k * 512 + (col - 512)];
            Wdf8[i] = (f16)v;
            continue;
        }
        i -= S2;
        if (i < 1024) { b_df[i] = (i < 512) ? b_dec[i] : b_fb[i - 512]; continue; }
        i -= 1024;
        b_cat[i] = b_ih[i] + b_hh[i];
    }
}

// ---------------- prep: tiled transpose W_fc -> W_fcT[n][k] fp16 ----------------
__global__ void k_tr_fc(const float* W_fc, f16* W_fcT) {
    __shared__ float tile[64][65];
    int n0 = blockIdx.x * 64;
    int k0 = blockIdx.y * 64;
    int t = threadIdx.x;
#pragma unroll
    for (int i = 0; i < 16; ++i) {
        int lin = t + i * 256;
        int kl = lin >> 6, nl = lin & 63;
        int n = n0 + nl;
        tile[kl][nl] = (n < 10000) ? W_fc[(long)(k0 + kl) * 10000 + n] : 0.0f;
    }
    __syncthreads();
#pragma unroll
    for (int i = 0; i < 2; ++i) {
        int lin = t + i * 256;
        int r = lin >> 3, cv = lin & 7;
        f16 v[8];
#pragma unroll
        for (int kr = 0; kr < 8; ++kr) v[kr] = (f16)tile[cv * 8 + kr][r];
        *(uint4*)&W_fcT[(long)(n0 + r) * 512 + k0 + cv * 8] = *(uint4*)v;
    }
}

// ---------------- prep: k8-repack [W_ih(top 512); W_hh] -> Wpart8 (K=1024) ----
__global__ void k_pack_part(const float* W_ih, const float* W_hh, f16* Wpart8) {
    __shared__ float tile[64][65];
    int k0 = blockIdx.x * 64;
    int n0 = blockIdx.y * 64;
    int t = threadIdx.x;
#pragma unroll
    for (int i = 0; i < 16; ++i) {
        int lin = t + i * 256;
        int kl = lin >> 6, nl = lin & 63;
        int k = k0 + kl;
        float v = (k < 512) ? W_ih[(long)k * 2048 + n0 + nl]
                            : W_hh[(long)(k - 512) * 2048 + n0 + nl];
        tile[kl][nl] = v;
    }
    __syncthreads();
#pragma unroll
    for (int i = 0; i < 2; ++i) {
        int lin = t + i * 256;
        int nl = lin & 63, k8l = lin >> 6;
        f16 v[8];
#pragma unroll
        for (int kr = 0; kr < 8; ++kr) v[kr] = (f16)tile[k8l * 8 + kr][nl];
        *(uint4*)&Wpart8[(long)(k0 / 8 + k8l) * 16384 + (long)(n0 + nl) * 8] = *(uint4*)v;
    }
}

// ---------------- prep: k8-repack W_ih(mid rows 512..1023) -> Wmid8 (K=512) ----------
__global__ void k_pack_mid(const float* W_ih, f16* Wmid8) {
    __shared__ float tile[64][65];
    int k0 = blockIdx.x * 64;
    int n0 = blockIdx.y * 64;
    int t = threadIdx.x;
#pragma unroll
    for (int i = 0; i < 16; ++i) {
        int lin = t + i * 256;
        int kl = lin >> 6, nl = lin & 63;
        tile[kl][nl] = W_ih[(long)(512 + k0 + kl) * 2048 + n0 + nl];
    }
    __syncthreads();
#pragma unroll
    for (int i = 0; i < 2; ++i) {
        int lin = t + i * 256;
        int nl = lin & 63, k8l = lin >> 6;
        f16 v[8];
#pragma unroll
        for (int kr = 0; kr < 8; ++kr) v[kr] = (f16)tile[k8l * 8 + kr][nl];
        *(uint4*)&Wmid8[(long)(k0 / 8 + k8l) * 16384 + (long)(n0 + nl) * 8] = *(uint4*)v;
    }
}

// ---------------- prep: enc transpose + mean ----------------
__global__ void k_prep_enc(const float* enc_out, f16* enc_t, float* mean_enc) {
    __shared__ float tile[64][197];
    int b = blockIdx.x >> 3, cc = blockIdx.x & 7, c0 = cc * 64;
    int t = threadIdx.x;
    const float* src = enc_out + ((long)b * 512 + c0) * 196;
    for (int i = 0; i < 49; ++i) {
        int lin = t + i * 256;
        int cl = lin / 196, p = lin % 196;
        tile[cl][p] = src[cl * 196 + p];
    }
    __syncthreads();
    if (t < 64) {
        float s = 0.f;
        for (int p = 0; p < 196; ++p) s += tile[t][p];
        mean_enc[b * 512 + c0 + t] = s * (1.0f / 196.0f);
    }
    __syncthreads();
    int cl = t & 63, pg = t >> 6;
    for (int i = 0; i < 49; ++i) {
        int p = pg * 49 + i;
        enc_t[((long)(b * 196 + p)) * 512 + c0 + cl] = (f16)tile[cl][p];
    }
}

// ---------------- h0/c0 + barrier/tail init ----------------
__global__ void k_h0c0(const float* mean_enc, const float* W_init_h, const float* b_init_h,
                       const float* W_init_c, const float* b_init_c,
                       float* c, f16* h_h, f16* h_all, unsigned* bar) {
    if (blockIdx.x == 64) {
        int t = threadIdx.x;
        for (int i = t; i < 512; i += 256) bar[i] = 0u;
        for (int i = t; i < 32 * 512; i += 256) h_all[(long)2016 * 512 + i] = (f16)0.0f;
        return;
    }
    __shared__ float ms[512];
    int b = blockIdx.x >> 1, which = blockIdx.x & 1;
    const float* W = which ? W_init_c : W_init_h;
    const float* bb = which ? b_init_c : b_init_h;
    int t = threadIdx.x;
    ms[t] = mean_enc[b * 512 + t];
    ms[t + 256] = mean_enc[b * 512 + t + 256];
    __syncthreads();
    for (int jj = 0; jj < 2; ++jj) {
        int j = t + jj * 256;
        float acc = bb[j];
        for (int k = 0; k < 512; ++k) acc += ms[k] * W[k * 512 + j];
        if (which) c[b * 512 + j] = acc;
        else h_h[b * 512 + j] = (f16)acc;
    }
}

// ---------------- enc_att = enc @ W_enc_att + b (fp16 MFMA) ----------------
__global__ __launch_bounds__(256, 2) void k_encatt(const f16* A, const f16* Bt,
                                                   const float* bias, f16* Cout) {
    __shared__ __align__(16) f16 As[128 * 32];
    __shared__ __align__(16) f16 Bs[128 * 32];
    int m0 = blockIdx.x * 128, n0 = blockIdx.y * 128;
    int t = threadIdx.x, w = t >> 6, lane = t & 63;
    int wm = (w >> 1) * 64, wn = (w & 1) * 64;
    int lm = lane & 15, lq = lane >> 4;
    f4v acc[4][4];
    for (int mi = 0; mi < 4; ++mi)
        for (int ni = 0; ni < 4; ++ni) acc[mi][ni] = (f4v){0.f, 0.f, 0.f, 0.f};
    for (int kb = 0; kb < 512; kb += 32) {
        for (int i = 0; i < 2; ++i) {
            int li = t + i * 256;
            int row = li >> 2, q = li & 3;
            *(uint4*)&As[row * 32 + q * 8] = *(const uint4*)&A[(long)(m0 + row) * 512 + kb + q * 8];
            *(uint4*)&Bs[row * 32 + q * 8] = *(const uint4*)&Bt[(long)(n0 + row) * 512 + kb + q * 8];
        }
        __syncthreads();
        h8 af[4], bf[4];
        for (int i = 0; i < 4; ++i) {
            af[i] = *(const h8*)&As[(wm + i * 16 + lm) * 32 + lq * 8];
            bf[i] = *(const h8*)&Bs[(wn + i * 16 + lm) * 32 + lq * 8];
        }
        for (int mi = 0; mi < 4; ++mi)
            for (int ni = 0; ni < 4; ++ni)
                acc[mi][ni] = __builtin_amdgcn_mfma_f32_16x16x32_f16(af[mi], bf[ni], acc[mi][ni], 0, 0, 0);
        __syncthreads();
    }
    for (int mi = 0; mi < 4; ++mi)
        for (int ni = 0; ni < 4; ++ni)
            for (int r = 0; r < 4; ++r) {
                int row = m0 + wm + mi * 16 + lq * 4 + r;
                int col = n0 + wn + ni * 16 + lm;
                Cout[(long)row * 512 + col] = (f16)(acc[mi][ni][r] + bias[col]);
            }
}

// ---------------- final FC: preds = h_all @ W_fc + b_fc (fp16 MFMA, masked) ----------------
__global__ __launch_bounds__(256, 2) void k_fc(const f16* A, const f16* Bt, const float* bias,
                                               const int* cl, float* out) {
    __shared__ __align__(16) f16 As[128 * 32];
    __shared__ __align__(16) f16 Bs[128 * 32];
    int m0 = blockIdx.x * 128, n0 = blockIdx.y * 128;
    int t = threadIdx.x, w = t >> 6, lane = t & 63;
    int wm = (w >> 1) * 64, wn = (w & 1) * 64;
    int lm = lane & 15, lq = lane >> 4;

    bool myact = false;
    if (t < 128) {
        int row = m0 + t;
        if (row < 2016) {
            int b = row / 63, tt = row - b * 63;
            myact = tt < (cl[b] - 1);
        }
    }
    int anyact = __syncthreads_or((int)myact);
    if (!anyact) {
        for (int i = 0; i < 64; ++i) {
            int idx = t + i * 256;
            int row = m0 + (idx >> 7), col = n0 + (idx & 127);
            if (row < 2016 && col < 10000) out[(long)row * 10000 + col] = 0.0f;
        }
        return;
    }

    f4v acc[4][4];
    for (int mi = 0; mi < 4; ++mi)
        for (int ni = 0; ni < 4; ++ni) acc[mi][ni] = (f4v){0.f, 0.f, 0.f, 0.f};
    for (int kb = 0; kb < 512; kb += 32) {
        for (int i = 0; i < 2; ++i) {
            int li = t + i * 256;
            int row = li >> 2, q = li & 3;
            *(uint4*)&As[row * 32 + q * 8] = *(const uint4*)&A[(long)(m0 + row) * 512 + kb + q * 8];
            *(uint4*)&Bs[row * 32 + q * 8] = *(const uint4*)&Bt[(long)(n0 + row) * 512 + kb + q * 8];
        }
        __syncthreads();
        h8 af[4], bf[4];
        for (int i = 0; i < 4; ++i) {
            af[i] = *(const h8*)&As[(wm + i * 16 + lm) * 32 + lq * 8];
            bf[i] = *(const h8*)&Bs[(wn + i * 16 + lm) * 32 + lq * 8];
        }
        for (int mi = 0; mi < 4; ++mi)
            for (int ni = 0; ni < 4; ++ni)
                acc[mi][ni] = __builtin_amdgcn_mfma_f32_16x16x32_f16(af[mi], bf[ni], acc[mi][ni], 0, 0, 0);
        __syncthreads();
    }
    for (int mi = 0; mi < 4; ++mi)
        for (int ni = 0; ni < 4; ++ni)
            for (int r = 0; r < 4; ++r) {
                int row = m0 + wm + mi * 16 + lq * 4 + r;
                int col = n0 + wn + ni * 16 + lm;
                if (row < 2016 && col < 10000) {
                    int b = row / 63, tt = row - b * 63;
                    bool act = tt < (cl[b] - 1);
                    out[(long)row * 10000 + col] = act ? (acc[mi][ni][r] + bias[col]) : 0.0f;
                }
            }
}

// ---------------- persistent recurrent loop (3 barriers/step, 512-thread blocks) ------
// P1 (8 bg x 32 cg): [emb|h] staging; gate partials (K=1024, wave=K/8, 4 batches
//     per lane); dec/f_beta GEMV (32 cols) -> da_gp.
// P2 (32 b x 8 pg): 25 score rows + exp + partial weighted enc sums -> pawe/psum.
//     (softmax deferred: awe = sum(pawe)/sum(psum) in P3 — no max subtraction,
//      scores are O(5), exp safe in fp32)
// P3 (8 bg x 32 jg): combine pawe -> awe, f_beta gate -> xm (LDS); mid-GEMM
//     (K=512, wave=K/8, 4 batches/lane); + partials; LSTM pointwise -> h,c,h_all.
__global__ __launch_bounds__(512, 2) void k_loop(
    const f16* Wdf8, const float* b_df,
    const f16* Wpart8, const f16* Wmid8, const float* b_cat,
    const f16* enc_att_h, const f16* enc_t,
    const float* W_full, const float* emb, const int* caps, const int* cl,
    float* c, f16* h_h, float* da_gp, float* gp_part, float* pawe, float* psum,
    f16* h_all, unsigned* bar) {
    __shared__ __align__(16) unsigned xcat[4 * 512];   // P1 [emb|h] f16x2 (8 KB)
    __shared__ float gred[8 * 4 * 64];                 // P1 gate K-eighth partials
    __shared__ float dfred[512];                       // P1 df partials
    __shared__ float das2[512];                        // P2 dec_a
    __shared__ float es[32];                           // P2 exp(scores)
    __shared__ float ps4[4];                           // P3 1/sum(exp)
    __shared__ __align__(16) unsigned xms[4 * 256];    // P3 gated awe f16x2 (4 KB)
    __shared__ float g3[8 * 4 * 64];                   // P3 K-eighth partials
    __shared__ float gsm[256];                         // P3 gate values

    const int bid = blockIdx.x, t = threadIdx.x;
    const int lane = t & 63, w = t >> 6;
    unsigned* arrive = bar;
    unsigned* release = bar + 384;

    const int bg = bid >> 5, b0 = bg * 4;
    const int cg = bid & 31;            // P1 colgroup
    const int jg = bid & 31;            // P3 jgroup
    const int b2 = bid & 31, pg = bid >> 3 >= 0 ? (bid >> 5) : 0;  // P2 batch / pgroup

    // step-invariant preloads
    float4 wfa = *(const float4*)(W_full + lane * 8);
    float4 wfb = *(const float4*)(W_full + lane * 8 + 4);
    float bc_g = 0.f, bdf = 0.f;
    if (t < 256) bc_g = b_cat[cg * 64 + (t & 63)];
    else if (t < 384) ;
    if (t < 128) bdf = b_df[cg * 32 + (t & 31)];
    const int nc3 = ((t & 63) >> 4) * 512 + jg * 16 + (t & 15);  // P3 combine col (t<256)
    // P3 LSTM thread constants (t<32)
    const int myb = b0 + (t >> 3);
    const int mycl = (t < 32) ? cl[myb] : 0;
    const int jp = t & 7;
    const int j0 = jg * 16 + jp * 2;
    // GEMV wave/lane constants
    const int n1 = cg * 64 + lane;                                // P1 gate col
    const int n3 = (lane >> 4) * 512 + jg * 16 + (lane & 15);     // P3 gate col
    const int dfcol = cg * 32 + (lane & 31);                      // P1 df col
    const int ksub = lane >> 5, wb2 = w & 3, kh = w >> 2;         // P1 df split

    for (int step = 0; step < 63; ++step) {
        // ================= P1 =================
        {
#pragma unroll
            for (int i = 0; i < 2; ++i) {
                int idx = t + i * 512;
                int b = idx >> 8, off = idx & 255;
                int tok = caps[(b0 + b) * 64 + step];
                float2 ev = *(const float2*)(emb + (long)tok * 512 + off * 2);
                h2 pe; pe.x = (f16)ev.x; pe.y = (f16)ev.y;
                xcat[b * 512 + off] = h22u(pe);
                xcat[b * 512 + 256 + off] = agent_ld_u((const unsigned*)h_h + (b0 + b) * 256 + off);
            }
            __syncthreads();
            // gate partials: wave w -> K-eighth (16 k8), 4 batches per lane
            {
                const f16* wp = Wpart8 + (long)n1 * 8;
                float a0 = 0.f, a1 = 0.f, a2 = 0.f, a3 = 0.f;
                for (int kk = 0; kk < 16; ++kk) {
                    int k8 = w * 16 + kk;
                    uint4 wv = *(const uint4*)(wp + (long)k8 * 16384);
                    uint4 x0 = *(const uint4*)&xcat[0 * 512 + k8 * 4];
                    uint4 x1 = *(const uint4*)&xcat[1 * 512 + k8 * 4];
                    uint4 x2 = *(const uint4*)&xcat[2 * 512 + k8 * 4];
                    uint4 x3 = *(const uint4*)&xcat[3 * 512 + k8 * 4];
                    a0 = fdot2(u2h2(x0.x), u2h2(wv.x), a0);
                    a0 = fdot2(u2h2(x0.y), u2h2(wv.y), a0);
                    a0 = fdot2(u2h2(x0.z), u2h2(wv.z), a0);
                    a0 = fdot2(u2h2(x0.w), u2h2(wv.w), a0);
                    a1 = fdot2(u2h2(x1.x), u2h2(wv.x), a1);
                    a1 = fdot2(u2h2(x1.y), u2h2(wv.y), a1);
                    a1 = fdot2(u2h2(x1.z), u2h2(wv.z), a1);
                    a1 = fdot2(u2h2(x1.w), u2h2(wv.w), a1);
                    a2 = fdot2(u2h2(x2.x), u2h2(wv.x), a2);
                    a2 = fdot2(u2h2(x2.y), u2h2(wv.y), a2);
                    a2 = fdot2(u2h2(x2.z), u2h2(wv.z), a2);
                    a2 = fdot2(u2h2(x2.w), u2h2(wv.w), a2);
                    a3 = fdot2(u2h2(x3.x), u2h2(wv.x), a3);
                    a3 = fdot2(u2h2(x3.y), u2h2(wv.y), a3);
                    a3 = fdot2(u2h2(x3.z), u2h2(wv.z), a3);
                    a3 = fdot2(u2h2(x3.w), u2h2(wv.w), a3);
                }
                gred[(w * 4 + 0) * 64 + lane] = a0;
                gred[(w * 4 + 1) * 64 + lane] = a1;
                gred[(w * 4 + 2) * 64 + lane] = a2;
                gred[(w * 4 + 3) * 64 + lane] = a3;
            }
            // dec/f_beta: wave -> (batch wb2, K-half kh); lane -> (col, K-quarter ksub)
            {
                const f16* wdf = Wdf8 + (long)dfcol * 8;
                const unsigned* hx = &xcat[wb2 * 512 + 256];
                int kbase = kh * 32 + ksub * 16;
                float a = 0.f;
                for (int kk = 0; kk < 16; ++kk) {
                    int k8 = kbase + kk;
                    uint4 wv = *(const uint4*)(wdf + (long)k8 * 8192);
                    uint4 xv = *(const uint4*)&hx[k8 * 4];
                    a = fdot2(u2h2(xv.x), u2h2(wv.x), a);
                    a = fdot2(u2h2(xv.y), u2h2(wv.y), a);
                    a = fdot2(u2h2(xv.z), u2h2(wv.z), a);
                    a = fdot2(u2h2(xv.w), u2h2(wv.w), a);
                }
                dfred[(wb2 * 32 + (lane & 31)) * 4 + kh * 2 + ksub] = a;
            }
            __syncthreads();
            if (t < 256) {
                int b = t >> 6, col = t & 63;
                float v = bc_g;
#pragma unroll
                for (int ww = 0; ww < 8; ++ww) v += gred[(ww * 4 + b) * 64 + col];
                agent_st_f(gp_part + (long)(b0 + b) * 2048 + cg * 64 + col, v);
            }
            if (t < 128) {
                int b = t >> 5, col = t & 31;
                const float* dr = &dfred[(b * 32 + col) * 4];
                float v = dr[0] + dr[1] + dr[2] + dr[3] + bdf;
                agent_st_f(da_gp + (long)(b0 + b) * 1024 + cg * 32 + col, v);
            }
        }
        gbar(arrive, release, (unsigned)step * 3u + 1u);

        // ================= P2: scores + exp + partial weighted sums =================
        {
            das2[t] = agent_ld_f(da_gp + (long)b2 * 1024 + t);
            __syncthreads();
            float4 dv0 = *(const float4*)&das2[lane * 8];
            float4 dv1 = *(const float4*)&das2[lane * 8 + 4];
            int nr = 196 - pg * 25; nr = nr < 25 ? nr : 25;
#pragma unroll
            for (int i = 0; i < 4; ++i) {
                int r = w + i * 8;
                if (r < nr) {
                    int p = pg * 25 + r;
                    uint4 ev = *(const uint4*)(enc_att_h + ((long)b2 * 196 + p) * 512 + lane * 8);
                    h2 e0 = u2h2(ev.x), e1 = u2h2(ev.y), e2 = u2h2(ev.z), e3 = u2h2(ev.w);
                    float a = 0.f;
                    a += fmaxf((float)e0.x + dv0.x, 0.f) * wfa.x;
                    a += fmaxf((float)e0.y + dv0.y, 0.f) * wfa.y;
                    a += fmaxf((float)e1.x + dv0.z, 0.f) * wfa.z;
                    a += fmaxf((float)e1.y + dv0.w, 0.f) * wfa.w;
                    a += fmaxf((float)e2.x + dv1.x, 0.f) * wfb.x;
                    a += fmaxf((float)e2.y + dv1.y, 0.f) * wfb.y;
                    a += fmaxf((float)e3.x + dv1.z, 0.f) * wfb.z;
                    a += fmaxf((float)e3.y + dv1.w, 0.f) * wfb.w;
                    for (int m = 32; m; m >>= 1) a += __shfl_xor(a, m);
                    if (lane == 0) es[r] = expf(a);
                }
            }
            __syncthreads();
            {
                float acc = 0.f;
                const f16* ep = enc_t + ((long)b2 * 196 + pg * 25) * 512 + t;
                for (int r = 0; r < nr; ++r) acc += es[r] * (float)ep[(long)r * 512];
                agent_st_f(pawe + ((long)b2 * 8 + pg) * 512 + t, acc);
                if (t == 0) {
                    float s = 0.f;
                    for (int r = 0; r < nr; ++r) s += es[r];
                    agent_st_f(psum + b2 * 8 + pg, s);
                }
            }
        }
        gbar(arrive, release, (unsigned)step * 3u + 2u);

        // ================= P3 =================
        {
            if (t < 4) {
                float s = 0.f;
#pragma unroll
                for (int pgi = 0; pgi < 8; ++pgi)
                    s += agent_ld_f(psum + (b0 + t) * 8 + pgi);
                ps4[t] = 1.0f / s;
            }
            __syncthreads();
#pragma unroll
            for (int i = 0; i < 2; ++i) {
                int idx = t + i * 512;             // 0..1023 = 4 b x 256 c-pairs
                int bb = idx >> 8, cp = idx & 255;
                float sx = 0.f, sy = 0.f;
#pragma unroll
                for (int pgi = 0; pgi < 8; ++pgi) {
                    float2 v = u2f2(agent_ld_u64(
                        (const unsigned long long*)pawe + ((long)(b0 + bb) * 8 + pgi) * 256 + cp));
                    sx += v.x; sy += v.y;
                }
                float inv = ps4[bb];
                float2 fb = u2f2(agent_ld_u64(
                    (const unsigned long long*)da_gp + (long)(b0 + bb) * 512 + 256 + cp));
                h2 pa;
                pa.x = (f16)(sigf(fb.x) * sx * inv);
                pa.y = (f16)(sigf(fb.y) * sy * inv);
                xms[bb * 256 + cp] = h22u(pa);
            }
            __syncthreads();
            // mid-GEMM: wave -> K-eighth (8 k8), 4 batches per lane
            {
                const f16* wp = Wmid8 + (long)n3 * 8;
                float a0 = 0.f, a1 = 0.f, a2 = 0.f, a3 = 0.f;
                for (int kk = 0; kk < 8; ++kk) {
                    int k8 = w * 8 + kk;
                    uint4 wv = *(const uint4*)(wp + (long)k8 * 16384);
                    uint4 x0 = *(const uint4*)&xms[0 * 256 + k8 * 4];
                    uint4 x1 = *(const uint4*)&xms[1 * 256 + k8 * 4];
                    uint4 x2 = *(const uint4*)&xms[2 * 256 + k8 * 4];
                    uint4 x3 = *(const uint4*)&xms[3 * 256 + k8 * 4];
                    a0 = fdot2(u2h2(x0.x), u2h2(wv.x), a0);
                    a0 = fdot2(u2h2(x0.y), u2h2(wv.y), a0);
                    a0 = fdot2(u2h2(x0.z), u2h2(wv.z), a0);
                    a0 = fdot2(u2h2(x0.w), u2h2(wv.w), a0);
                    a1 = fdot2(u2h2(x1.x), u2h2(wv.x), a1);
                    a1 = fdot2(u2h2(x1.y), u2h2(wv.y), a1);
                    a1 = fdot2(u2h2(x1.z), u2h2(wv.z), a1);
                    a1 = fdot2(u2h2(x1.w), u2h2(wv.w), a1);
                    a2 = fdot2(u2h2(x2.x), u2h2(wv.x), a2);
                    a2 = fdot2(u2h2(x2.y), u2h2(wv.y), a2);
                    a2 = fdot2(u2h2(x2.z), u2h2(wv.z), a2);
                    a2 = fdot2(u2h2(x2.w), u2h2(wv.w), a2);
                    a3 = fdot2(u2h2(x3.x), u2h2(wv.x), a3);
                    a3 = fdot2(u2h2(x3.y), u2h2(wv.y), a3);
                    a3 = fdot2(u2h2(x3.z), u2h2(wv.z), a3);
                    a3 = fdot2(u2h2(x3.w), u2h2(wv.w), a3);
                }
                g3[(w * 4 + 0) * 64 + lane] = a0;
                g3[(w * 4 + 1) * 64 + lane] = a1;
                g3[(w * 4 + 2) * 64 + lane] = a2;
                g3[(w * 4 + 3) * 64 + lane] = a3;
            }
            __syncthreads();
            if (t < 256) {
                int b = t >> 6, l2 = t & 63;
                float v = agent_ld_f(gp_part + (long)(b0 + b) * 2048 + nc3);
#pragma unroll
                for (int ww = 0; ww < 8; ++ww) v += g3[(ww * 4 + b) * 64 + l2];
                gsm[b * 64 + l2] = v;
            }
            __syncthreads();
            if (t < 32) {
                int bl = t >> 3;
                int l0 = jp * 2, l1 = jp * 2 + 1;
                float gi0 = gsm[bl * 64 + l0],      gi1 = gsm[bl * 64 + l1];
                float gf0 = gsm[bl * 64 + 16 + l0], gf1 = gsm[bl * 64 + 16 + l1];
                float gg0 = gsm[bl * 64 + 32 + l0], gg1 = gsm[bl * 64 + 32 + l1];
                float go0 = gsm[bl * 64 + 48 + l0], go1 = gsm[bl * 64 + 48 + l1];
                float2 cold = *(float2*)(c + (long)myb * 512 + j0);
                float cn0 = sigf(gf0) * cold.x + sigf(gi0) * tanhf(gg0);
                float hn0 = sigf(go0) * tanhf(cn0);
                float cn1 = sigf(gf1) * cold.y + sigf(gi1) * tanhf(gg1);
                float hn1 = sigf(go1) * tanhf(cn1);
                h2 oldh = u2h2(agent_ld_u((const unsigned*)h_h + myb * 256 + (j0 >> 1)));
                bool act = step < (mycl - 1);
                float hv0, hv1, cv0, cv1;
                if (act) { hv0 = hn0; hv1 = hn1; cv0 = cn0; cv1 = cn1; }
                else { hv0 = (float)oldh.x; hv1 = (float)oldh.y; cv0 = cold.x; cv1 = cold.y; }
                float2 cw; cw.x = cv0; cw.y = cv1;
                *(float2*)(c + (long)myb * 512 + j0) = cw;
                h2 hp; hp.x = (f16)hv0; hp.y = (f16)hv1;
                unsigned pv = h22u(hp);
                agent_st_u((unsigned*)h_h + myb * 256 + (j0 >> 1), pv);
                *((unsigned*)h_all + ((long)myb * 63 + step) * 256 + (j0 >> 1)) = pv;
            }
        }
        gbar(arrive, release, (unsigned)step * 3u + 3u);
    }
}

// ---------------- launcher ----------------
extern "C" void kernel_launch(void* const* d_in, const int* in_sizes, int n_in,
                              void* d_out, int out_size, void* d_ws, size_t ws_size,
                              hipStream_t stream) {
    const float* encoder_out = (const float*)d_in[0];
    const int* caps = (const int*)d_in[1];
    const int* cl = (const int*)d_in[2];
    const float* emb = (const float*)d_in[3];
    const float* W_enc_att = (const float*)d_in[4];
    const float* b_enc_att = (const float*)d_in[5];
    const float* W_dec_att = (const float*)d_in[6];
    const float* b_dec_att = (const float*)d_in[7];
    const float* W_full_att = (const float*)d_in[8];
    const float* W_init_h = (const float*)d_in[10];
    const float* b_init_h = (const float*)d_in[11];
    const float* W_init_c = (const float*)d_in[12];
    const float* b_init_c = (const float*)d_in[13];
    const float* W_f_beta = (const float*)d_in[14];
    const float* b_f_beta = (const float*)d_in[15];
    const float* W_ih = (const float*)d_in[16];
    const float* b_ih = (const float*)d_in[17];
    const float* W_hh = (const float*)d_in[18];
    const float* b_hh = (const float*)d_in[19];
    const float* W_fc = (const float*)d_in[20];
    const float* b_fc = (const float*)d_in[21];

    char* p = (char*)d_ws;
    auto take = [&](size_t bytes) {
        char* r = p;
        p += (bytes + 255) & ~(size_t)255;
        return r;
    };
    f16* enc_t     = (f16*)take((size_t)32 * 196 * 512 * 2);
    f16* enc_att_h = (f16*)take((size_t)32 * 196 * 512 * 2);
    f16* W_encT    = (f16*)take((size_t)512 * 512 * 2);
    f16* W_fcT     = (f16*)take((size_t)10112 * 512 * 2);
    f16* Wdf8      = (f16*)take((size_t)512 * 1024 * 2);
    f16* Wpart8    = (f16*)take((size_t)1024 * 2048 * 2);
    f16* Wmid8     = (f16*)take((size_t)512 * 2048 * 2);
    f16* h_all     = (f16*)take((size_t)2048 * 512 * 2);
    f16* h_h       = (f16*)take((size_t)32 * 512 * 2);
    float* b_df    = (float*)take(1024 * 4);
    float* b_cat   = (float*)take(2048 * 4);
    float* mean_e  = (float*)take((size_t)32 * 512 * 4);
    float* c_st    = (float*)take((size_t)32 * 512 * 4);
    float* da_gp   = (float*)take((size_t)32 * 1024 * 4);
    float* gp_part = (float*)take((size_t)32 * 2048 * 4);
    float* pawe    = (float*)take((size_t)32 * 8 * 512 * 4);
    float* psum    = (float*)take((size_t)256 * 4);
    unsigned* bar  = (unsigned*)take(2048);

    k_prep_w<<<1024, 256, 0, stream>>>(W_enc_att, W_dec_att, W_f_beta,
                                       b_dec_att, b_f_beta, b_ih, b_hh,
                                       W_encT, Wdf8, b_df, b_cat);
    k_tr_fc<<<dim3(158, 8), 256, 0, stream>>>(W_fc, W_fcT);
    k_pack_part<<<dim3(16, 32), 256, 0, stream>>>(W_ih, W_hh, Wpart8);
    k_pack_mid<<<dim3(8, 32), 256, 0, stream>>>(W_ih, Wmid8);
    k_prep_enc<<<256, 256, 0, stream>>>(encoder_out, enc_t, mean_e);
    k_h0c0<<<65, 256, 0, stream>>>(mean_e, W_init_h, b_init_h, W_init_c, b_init_c,
                                   c_st, h_h, h_all, bar);
    k_encatt<<<dim3(49, 4), 256, 0, stream>>>(enc_t, W_encT, b_enc_att, enc_att_h);
    k_loop<<<256, 512, 0, stream>>>(Wdf8, b_df, Wpart8, Wmid8, b_cat,
                                    enc_att_h, enc_t, W_full_att, emb, caps, cl,
                                    c_st, h_h, da_gp, gp_part, pawe, psum, h_all, bar);
    k_fc<<<dim3(16, 79), 256, 0, stream>>>(h_all, W_fcT, b_fc, cl, (float*)d_out);
}